// Round 10
// baseline (138.361 us; speedup 1.0000x reference)
//
#include <hip/hip_runtime.h>
#include <hip/hip_bf16.h>

using bf16x8 = __attribute__((ext_vector_type(8))) __bf16;
using f32x4  = __attribute__((ext_vector_type(4))) float;
using f32x16 = __attribute__((ext_vector_type(16))) float;
using i32x4  = __attribute__((ext_vector_type(4))) int;

#define MFMA_16x16x32(a, b, c) __builtin_amdgcn_mfma_f32_16x16x32_bf16((a), (b), (c), 0, 0, 0)
#define MFMA32(a, b, c)        __builtin_amdgcn_mfma_f32_32x32x16_bf16((a), (b), (c), 0, 0, 0)

__device__ __forceinline__ ushort f2bf(float f) {
    return __builtin_bit_cast(ushort, (__bf16)f);
}
__device__ __forceinline__ unsigned pk_bf16(float lo, float hi) {
    unsigned r;
    asm volatile("v_cvt_pk_bf16_f32 %0, %1, %2" : "=v"(r) : "v"(lo), "v"(hi));
    return r;
}
__device__ __forceinline__ void pl32_swap(unsigned &a, unsigned &b) {
    asm volatile("v_permlane32_swap_b32 %0, %1" : "+v"(a), "+v"(b));
}

// ---------------------------------------------------------------------------
// fp32 -> bf16 vectorized convert (8 elems/thread)
// ---------------------------------------------------------------------------
__global__ __launch_bounds__(256) void cvt_bf16(
    const float* __restrict__ in, ushort* __restrict__ out, int n)
{
    const int i = (blockIdx.x * 256 + threadIdx.x) * 8;
    if (i + 8 <= n) {
        const f32x4 a = *(const f32x4*)(in + i);
        const f32x4 b = *(const f32x4*)(in + i + 4);
        union { ushort u[8]; i32x4 w; } p;
        #pragma unroll
        for (int j = 0; j < 4; ++j) { p.u[j] = f2bf(a[j]); p.u[4 + j] = f2bf(b[j]); }
        *(i32x4*)(out + i) = p.w;
    }
}

// ---------------------------------------------------------------------------
// 3x QKV weights fp32 -> bf16, concat into wbf[3][512*512]
// ---------------------------------------------------------------------------
__global__ __launch_bounds__(256) void cvt_w3(
    const float* __restrict__ w0, const float* __restrict__ w1,
    const float* __restrict__ w2, ushort* __restrict__ out)
{
    const int i = (blockIdx.x * 256 + threadIdx.x) * 8;   // < 3*262144
    const int w = i >> 18, off = i & 262143;
    const float* src = (w == 0) ? w0 : ((w == 1) ? w1 : w2);
    const f32x4 a = *(const f32x4*)(src + off);
    const f32x4 b = *(const f32x4*)(src + off + 4);
    union { ushort u[8]; i32x4 v; } p;
    #pragma unroll
    for (int j = 0; j < 4; ++j) { p.u[j] = f2bf(a[j]); p.u[4 + j] = f2bf(b[j]); }
    *(i32x4*)(out + i) = p.v;
}

// ---------------------------------------------------------------------------
// Fused QKV GEMM (pipelined staging): C = A(bf16) * Wbf(bf16)^T * scale
// blockIdx.y: (y>>2) selects {Wq,Wk,Wv}; (y&3) is the 128-col n-tile.
// q,k -> bf16 head-interleaved [b,h,t,64]; v -> TRANSPOSED [b,h,d,2048]
// ---------------------------------------------------------------------------
__global__ __launch_bounds__(256) void gemm_qkv3(
    const ushort* __restrict__ A, const ushort* __restrict__ Wbf,
    float qscale, ushort* __restrict__ qb, ushort* __restrict__ kb,
    ushort* __restrict__ vb)
{
    __shared__ ushort lA[128][40];
    __shared__ ushort lB[128][40];
    const int wsel = blockIdx.y >> 2;
    const int n0 = (blockIdx.y & 3) * 128;
    const ushort* W = Wbf + wsel * 262144;
    ushort* out = (wsel == 0) ? qb : ((wsel == 1) ? kb : vb);
    const float scale = (wsel == 0) ? qscale : 1.0f;

    const int m0 = blockIdx.x * 128;
    const int tid  = threadIdx.x;
    const int lane = tid & 63;
    const int wave = tid >> 6;
    const int wr = (wave >> 1) * 64, wc = (wave & 1) * 64;
    const int frow = lane & 15, fk = (lane >> 4) * 8;
    const int sr = tid >> 1, scc = (tid & 1) * 16;

    f32x4 acc[4][4] = {};
    i32x4 va0, va1, vb0, vb1;
    auto load = [&](int k0) {
        const ushort* pa = A + (m0 + sr) * 512 + k0 + scc;
        va0 = *(const i32x4*)(pa);
        va1 = *(const i32x4*)(pa + 8);
        const ushort* pb = W + (n0 + sr) * 512 + k0 + scc;
        vb0 = *(const i32x4*)(pb);
        vb1 = *(const i32x4*)(pb + 8);
    };

    load(0);
    for (int t = 0; t < 16; ++t) {
        __syncthreads();                       // prior step's LDS reads done
        *(i32x4*)&lA[sr][scc]     = va0;
        *(i32x4*)&lA[sr][scc + 8] = va1;
        *(i32x4*)&lB[sr][scc]     = vb0;
        *(i32x4*)&lB[sr][scc + 8] = vb1;
        if (t + 1 < 16) load((t + 1) * 32);    // next step hides under compute
        __syncthreads();

        bf16x8 af[4], bg[4];
        #pragma unroll
        for (int m = 0; m < 4; ++m) af[m] = *(const bf16x8*)&lA[wr + m * 16 + frow][fk];
        #pragma unroll
        for (int n = 0; n < 4; ++n) bg[n] = *(const bf16x8*)&lB[wc + n * 16 + frow][fk];
        #pragma unroll
        for (int m = 0; m < 4; ++m)
            #pragma unroll
            for (int n = 0; n < 4; ++n)
                acc[m][n] = MFMA_16x16x32(af[m], bg[n], acc[m][n]);
    }

    const int rbase = (lane >> 4) * 4;
    const int ccol  = lane & 15;
    if (wsel == 2) {
        // V transposed: vt[((b*8+h)*64 + d)*2048 + t], pack 4 consecutive t
        #pragma unroll
        for (int m = 0; m < 4; ++m)
            #pragma unroll
            for (int n = 0; n < 4; ++n) {
                const int col = n0 + wc + n * 16 + ccol;
                const int row0 = m0 + wr + m * 16 + rbase;
                unsigned long long u = 0;
                #pragma unroll
                for (int r = 0; r < 4; ++r)
                    u |= ((unsigned long long)f2bf(acc[m][n][r])) << (16 * r);
                const size_t idx = ((size_t)((row0 >> 11) * 8 + (col >> 6)) * 64
                                    + (col & 63)) * 2048 + (row0 & 2047);
                *(unsigned long long*)(out + idx) = u;
            }
    } else {
        #pragma unroll
        for (int m = 0; m < 4; ++m)
            #pragma unroll
            for (int n = 0; n < 4; ++n) {
                const int col = n0 + wc + n * 16 + ccol;
                #pragma unroll
                for (int r = 0; r < 4; ++r) {
                    const int row = m0 + wr + m * 16 + rbase + r;
                    out[(((row >> 11) * 8 + (col >> 6)) * 2048 + (row & 2047)) * 64 + (col & 63)]
                        = f2bf(acc[m][n][r] * scale);
                }
            }
    }
}

// ---------------------------------------------------------------------------
// Output GEMM (pipelined staging): C[M,512](fp32) = A(bf16, head-il) * Wp^T + bp
// ---------------------------------------------------------------------------
__global__ __launch_bounds__(256) void gemm_out(
    const ushort* __restrict__ A, const float* __restrict__ W,
    const float* __restrict__ bias, float* __restrict__ out)
{
    __shared__ ushort lA[128][40];
    __shared__ ushort lB[128][40];
    const int m0 = blockIdx.x * 128;
    const int n0 = blockIdx.y * 128;
    const int tid  = threadIdx.x;
    const int lane = tid & 63;
    const int wave = tid >> 6;
    const int wr = (wave >> 1) * 64, wc = (wave & 1) * 64;
    const int frow = lane & 15, fk = (lane >> 4) * 8;
    const int sr = tid >> 1, scc = (tid & 1) * 16;

    f32x4 acc[4][4] = {};
    i32x4 va0, va1;
    f32x4 b0, b1, b2, b3;
    auto load = [&](int k0) {
        const int row = m0 + sr, c = k0 + scc;
        const ushort* pa = A + ((((row >> 11) * 8 + (c >> 6)) * 2048 + (row & 2047)) * 64 + (c & 63));
        va0 = *(const i32x4*)(pa);
        va1 = *(const i32x4*)(pa + 8);
        const float* pb = W + (n0 + sr) * 512 + k0 + scc;
        b0 = *(const f32x4*)(pb);
        b1 = *(const f32x4*)(pb + 4);
        b2 = *(const f32x4*)(pb + 8);
        b3 = *(const f32x4*)(pb + 12);
    };

    load(0);
    for (int t = 0; t < 16; ++t) {
        union { ushort u[16]; i32x4 w[2]; } pB;
        #pragma unroll
        for (int j = 0; j < 4; ++j) {
            pB.u[j]      = f2bf(b0[j]);  pB.u[4 + j]  = f2bf(b1[j]);
            pB.u[8 + j]  = f2bf(b2[j]);  pB.u[12 + j] = f2bf(b3[j]);
        }
        __syncthreads();
        *(i32x4*)&lA[sr][scc]     = va0;
        *(i32x4*)&lA[sr][scc + 8] = va1;
        *(i32x4*)&lB[sr][scc]     = pB.w[0];
        *(i32x4*)&lB[sr][scc + 8] = pB.w[1];
        if (t + 1 < 16) load((t + 1) * 32);
        __syncthreads();

        bf16x8 af[4], bg[4];
        #pragma unroll
        for (int m = 0; m < 4; ++m) af[m] = *(const bf16x8*)&lA[wr + m * 16 + frow][fk];
        #pragma unroll
        for (int n = 0; n < 4; ++n) bg[n] = *(const bf16x8*)&lB[wc + n * 16 + frow][fk];
        #pragma unroll
        for (int m = 0; m < 4; ++m)
            #pragma unroll
            for (int n = 0; n < 4; ++n)
                acc[m][n] = MFMA_16x16x32(af[m], bg[n], acc[m][n]);
    }

    const int rbase = (lane >> 4) * 4;
    const int ccol  = lane & 15;
    #pragma unroll
    for (int m = 0; m < 4; ++m)
        #pragma unroll
        for (int n = 0; n < 4; ++n) {
            const int col = n0 + wc + n * 16 + ccol;
            const float bv = bias[col];
            #pragma unroll
            for (int r = 0; r < 4; ++r) {
                const int row = m0 + wr + m * 16 + rbase + r;
                out[row * 512 + col] = acc[m][n][r] + bv;
            }
        }
}

// ---------------------------------------------------------------------------
// Causal flash attention R10: split-KV 8-wave blocks. 512 threads, 128 q-rows.
// Wave (g,h): g=wv>>1 owns rows [qt0+g*32,+32); h=wv&1 processes KV tiles of
// parity h. End-of-block (m,l,O) merge via LDS. K staged by h==0 waves, V by
// h==1 waves. Math identical to R7/R9. q,k: [bh][t][64]; vt: [bh][d][2048].
// ---------------------------------------------------------------------------
__global__ __launch_bounds__(512) void attn_kernel(
    const ushort* __restrict__ q, const ushort* __restrict__ k,
    const ushort* __restrict__ vt, ushort* __restrict__ att)
{
    __shared__ ushort lds[2][2][64][64];   // [K/V][buf][row][64], 32 KB
    __shared__ float  mml[4][2][64];       // [g][{m,l}][lane]

    const int NB   = (int)(gridDim.x * gridDim.y);
    const int NH   = NB >> 4;            // number of bh slices (16 q-tiles)
    const int half = NB >> 1;
    const int n    = (int)(blockIdx.y * gridDim.x + blockIdx.x);
    const int r    = (n < half) ? n : (NB - 1 - (n - half));
    const int qt0  = (15 - r / NH) * 128;    // heavy-first
    const int bh   = r % NH;

    const ushort* Q  = q  + (size_t)bh * 2048 * 64;
    const ushort* K  = k  + (size_t)bh * 2048 * 64;
    const ushort* VT = vt + (size_t)bh * 2048 * 64;
    ushort* O = att + (size_t)bh * 2048 * 64;

    const int tid = threadIdx.x;
    const int wv  = tid >> 6;            // 0..7
    const int g   = wv >> 1;             // row group 0..3
    const int h   = wv & 1;              // KV parity
    const int l   = tid & 63;
    const int ql  = l & 31;
    const int hi  = l >> 5;
    const int wrow0 = qt0 + g * 32;
    const int qrow  = wrow0 + ql;
    const int wmax  = wrow0 + 31;
    const int qkey  = ql & 7;
    const float LOG2E = 1.44269504088896f;

    // staging: h==0 waves stage K, h==1 stage V. 256 staging lanes per side.
    const int pid  = g * 64 + l;         // 0..255
    const int srow = pid >> 2;
    const int sg   = (pid & 3) * 2;
    const int skey = srow & 7;

    bf16x8 aq[4];
    #pragma unroll
    for (int kk = 0; kk < 4; ++kk)
        aq[kk] = *(const bf16x8*)(Q + (size_t)qrow * 64 + kk * 16 + hi * 8);

    f32x16 o0 = {}, o1 = {};
    float mrun = -30000.0f, lrun = 0.0f;
    const int nt = qt0 / 64 + 2;

    i32x4 sr0, sr1;                      // staging registers (K or V role)
    auto loadG = [&](int s0) {
        const ushort* p = h ? (VT + (size_t)srow * 2048 + s0 + sg * 8)
                            : (K + (size_t)(s0 + srow) * 64 + sg * 8);
        sr0 = *(const i32x4*)(p);
        sr1 = *(const i32x4*)(p + 8);
    };
    auto writeL = [&](int b) {
        *(i32x4*)&lds[h][b][srow][((sg    ) ^ skey) * 8] = sr0;
        *(i32x4*)&lds[h][b][srow][((sg + 1) ^ skey) * 8] = sr1;
    };

    loadG(0);
    writeL(0);
    if (nt > 1) loadG(64);               // tile 1 in regs across iter 0

    for (int t = 0; t < nt; ++t) {
        const int p  = t & 1;
        const int s0 = t * 64;
        __syncthreads();                  // buf[p] visible; buf[p^1] drained
        if (t + 1 < nt) writeL(p ^ 1);    // regs (tile t+1) -> LDS
        if (t + 2 < nt) loadG(s0 + 128);  // issue tile t+2, lands next iter

        if (((t ^ h) & 1) || s0 > wmax) continue;   // other parity / masked

        // S^T = K * Q^T from LDS (swizzled reads)
        f32x16 sa = {}, sb = {};
        #pragma unroll
        for (int kk = 0; kk < 4; ++kk) {
            const bf16x8 kb0 = *(const bf16x8*)&lds[0][p][ql]     [((2 * kk + hi) ^ qkey) * 8];
            const bf16x8 kb1 = *(const bf16x8*)&lds[0][p][32 + ql][((2 * kk + hi) ^ qkey) * 8];
            sa = MFMA32(kb0, aq[kk], sa);
            sb = MFMA32(kb1, aq[kk], sb);
        }

        if (s0 + 63 > wrow0) {            // tile intersects this wave's diagonal
            #pragma unroll
            for (int rr = 0; rr < 16; ++rr) {
                const int cr = (rr & 3) + 8 * (rr >> 2) + 4 * hi;
                if (s0 + cr > qrow)      sa[rr] = -30000.0f;
                if (s0 + 32 + cr > qrow) sb[rr] = -30000.0f;
            }
        }

        // row max (lane-local rows): 31 fmax + 1 cross-half shuffle
        float pmax = sa[0];
        #pragma unroll
        for (int rr = 1; rr < 16; ++rr) pmax = fmaxf(pmax, sa[rr]);
        #pragma unroll
        for (int rr = 0; rr < 16; ++rr) pmax = fmaxf(pmax, sb[rr]);
        pmax = fmaxf(pmax, __shfl_xor(pmax, 32));

        // defer-max (T13)
        if (__any(pmax > mrun + 8.0f)) {
            const float mnew  = fmaxf(mrun, pmax);
            const float alpha = exp2f((mrun - mnew) * LOG2E);
            mrun = mnew;
            lrun *= alpha;
            #pragma unroll
            for (int rr = 0; rr < 16; ++rr) {
                const float ar = __shfl(alpha, (rr & 3) + 8 * (rr >> 2) + 4 * hi);
                o0[rr] *= ar; o1[rr] *= ar;
            }
        }

        const float mb = mrun * LOG2E;
        float ps = 0.0f;
        #pragma unroll
        for (int rr = 0; rr < 16; ++rr) {
            sa[rr] = exp2f(fmaf(sa[rr], LOG2E, -mb));
            sb[rr] = exp2f(fmaf(sb[rr], LOG2E, -mb));
            ps += sa[rr] + sb[rr];
        }
        ps += __shfl_xor(ps, 32);
        lrun += ps;

        // P -> PV A-fragments (T12)
        unsigned paw[4][4];
        #pragma unroll
        for (int ks = 0; ks < 4; ++ks) {
            const int e = 2 * ks, f = 2 * ks + 1;
            const int ra = 4 * (e & 3), rb = 4 * (f & 3);
            unsigned A0, A1, B0, B1;
            if (e >> 2) { A0 = pk_bf16(sb[ra], sb[ra + 1]); A1 = pk_bf16(sb[ra + 2], sb[ra + 3]); }
            else        { A0 = pk_bf16(sa[ra], sa[ra + 1]); A1 = pk_bf16(sa[ra + 2], sa[ra + 3]); }
            if (f >> 2) { B0 = pk_bf16(sb[rb], sb[rb + 1]); B1 = pk_bf16(sb[rb + 2], sb[rb + 3]); }
            else        { B0 = pk_bf16(sa[rb], sa[rb + 1]); B1 = pk_bf16(sa[rb + 2], sa[rb + 3]); }
            pl32_swap(A0, B0);
            pl32_swap(A1, B1);
            paw[ks][0] = A0; paw[ks][1] = A1; paw[ks][2] = B0; paw[ks][3] = B1;
        }

        // O += P * V from LDS V^T tile (swizzled reads)
        #pragma unroll
        for (int ks = 0; ks < 4; ++ks) {
            union { unsigned w[4]; bf16x8 v; } u;
            u.w[0] = paw[ks][0]; u.w[1] = paw[ks][1];
            u.w[2] = paw[ks][2]; u.w[3] = paw[ks][3];
            const bf16x8 v0 = *(const bf16x8*)&lds[1][p][ql]     [((2 * ks + hi) ^ qkey) * 8];
            const bf16x8 v1 = *(const bf16x8*)&lds[1][p][32 + ql][((2 * ks + hi) ^ qkey) * 8];
            o0 = MFMA32(u.v, v0, o0);
            o1 = MFMA32(u.v, v1, o1);
        }
    }

    // ---- merge partner parities (g,0) <- (g,1), then write output ----
    __syncthreads();                      // all tile compute / LDS reads done
    float* mo = (float*)lds;              // 8192 floats == 32 KB, reuse K/V
    if (h == 1) {
        float* base = mo + g * 2048 + l * 32;
        #pragma unroll
        for (int rr = 0; rr < 16; ++rr) {
            base[(rr + l) & 31]      = o0[rr];   // rotation: conflict-free
            base[(16 + rr + l) & 31] = o1[rr];
        }
        mml[g][0][l] = mrun;
        mml[g][1][l] = lrun;
    }
    __syncthreads();
    if (h == 0) {
        const float m1 = mml[g][0][l];
        const float l1 = mml[g][1][l];
        const float mm = fmaxf(mrun, m1);
        const float a0 = exp2f((mrun - mm) * LOG2E);
        const float a1 = exp2f((m1 - mm) * LOG2E);
        const float lm   = lrun * a0 + l1 * a1;
        const float linv = 1.0f / fmaxf(lm, 1e-30f);
        const float* base = mo + g * 2048 + l * 32;
        #pragma unroll
        for (int rr = 0; rr < 16; ++rr) {
            const int cr = (rr & 3) + 8 * (rr >> 2) + 4 * hi;
            const float a0r = __shfl(a0, cr);
            const float a1r = __shfl(a1, cr);
            const float lir = __shfl(linv, cr);
            const float po0 = base[(rr + l) & 31];
            const float po1 = base[(16 + rr + l) & 31];
            const int row = wrow0 + cr;
            O[(size_t)row * 64 + ql]      = f2bf((o0[rr] * a0r + po0 * a1r) * lir);
            O[(size_t)row * 64 + 32 + ql] = f2bf((o1[rr] * a0r + po1 * a1r) * lir);
        }
    }
}

extern "C" void kernel_launch(void* const* d_in, const int* in_sizes, int n_in,
                              void* d_out, int out_size, void* d_ws, size_t ws_size,
                              hipStream_t stream) {
    const float* x  = (const float*)d_in[0];   // x_q  [4,2048,512] fp32
    const float* Wq = (const float*)d_in[1];   // [8,64,512] fp32
    const float* Wk = (const float*)d_in[2];
    const float* Wv = (const float*)d_in[3];
    const float* Wp = (const float*)d_in[4];   // [512,512] fp32
    const float* bp = (const float*)d_in[5];   // [512] fp32
    float* out = (float*)d_out;                // [4,2048,512] fp32

    const size_t NEL  = 4u * 8u * 2048u * 64u;   // 4,194,304 (all batches)
    const size_t NELB = 8u * 2048u * 64u;        // 1,048,576 (one batch)
    const float qscale = 0.04419417382415922f;   // 512^-0.5 folded into q

    if (ws_size >= 3u * NEL * sizeof(ushort)) {
        // d_out bytes: [xbf (bf16 x)][qb (bf16 q)] — final GEMM overwrites.
        // wbf (bf16 QKV weights) parks at ab; attn overwrites ab only later.
        ushort* xbf = (ushort*)d_out;
        ushort* qb  = xbf + NEL;
        ushort* kb  = (ushort*)d_ws;
        ushort* vb  = kb + NEL;                  // holds VT [b,h,d,2048]
        ushort* ab  = vb + NEL;
        ushort* wbf = ab;                        // 3*262144 ushorts = 1.5 MB
        hipLaunchKernelGGL(cvt_bf16, dim3((int)(NEL / (256 * 8))), dim3(256), 0, stream,
                           x, xbf, (int)NEL);
        hipLaunchKernelGGL(cvt_w3, dim3(384), dim3(256), 0, stream, Wq, Wk, Wv, wbf);
        hipLaunchKernelGGL(gemm_qkv3, dim3(64, 12), dim3(256), 0, stream,
                           xbf, wbf, qscale, qb, kb, vb);
        hipLaunchKernelGGL(attn_kernel, dim3(16, 32), dim3(512), 0, stream, qb, kb, vb, ab);
        hipLaunchKernelGGL(gemm_out, dim3(64, 4), dim3(256), 0, stream, ab, Wp, bp, out);
    } else {
        // per-batch fallback: ws need = 3 * NELB * 2 = 6.3 MB
        ushort* kb = (ushort*)d_ws;
        ushort* vb = kb + NELB;
        ushort* ab = vb + NELB;
        ushort* wbf = ab;                        // 1.5 MB <= 2 MB slice
        for (int b = 0; b < 4; ++b) {
            const float* xb = x + (size_t)b * 2048u * 512u;
            float* ob = out + (size_t)b * 2048u * 512u;
            ushort* xbf = (ushort*)ob;           // batch slice: [xbf][qb]
            ushort* qb  = xbf + NELB;
            hipLaunchKernelGGL(cvt_bf16, dim3((int)(NELB / (256 * 8))), dim3(256), 0, stream,
                               xb, xbf, (int)NELB);
            hipLaunchKernelGGL(cvt_w3, dim3(384), dim3(256), 0, stream, Wq, Wk, Wv, wbf);
            hipLaunchKernelGGL(gemm_qkv3, dim3(16, 12), dim3(256), 0, stream,
                               xbf, wbf, qscale, qb, kb, vb);
            hipLaunchKernelGGL(attn_kernel, dim3(16, 8), dim3(512), 0, stream, qb, kb, vb, ab);
            hipLaunchKernelGGL(gemm_out, dim3(16, 4), dim3(256), 0, stream, ab, Wp, bp, ob);
        }
    }
}

// Round 12
// 107.881 us; speedup vs baseline: 1.2825x; 1.2825x over previous
//
#include <hip/hip_runtime.h>
#include <hip/hip_bf16.h>

using bf16x8 = __attribute__((ext_vector_type(8))) __bf16;
using f32x4  = __attribute__((ext_vector_type(4))) float;
using f32x16 = __attribute__((ext_vector_type(16))) float;
using i32x4  = __attribute__((ext_vector_type(4))) int;

#define MFMA_16x16x32(a, b, c) __builtin_amdgcn_mfma_f32_16x16x32_bf16((a), (b), (c), 0, 0, 0)
#define MFMA32(a, b, c)        __builtin_amdgcn_mfma_f32_32x32x16_bf16((a), (b), (c), 0, 0, 0)

__device__ __forceinline__ ushort f2bf(float f) {
    return __builtin_bit_cast(ushort, (__bf16)f);
}
__device__ __forceinline__ unsigned pk_bf16(float lo, float hi) {
    unsigned r;
    asm volatile("v_cvt_pk_bf16_f32 %0, %1, %2" : "=v"(r) : "v"(lo), "v"(hi));
    return r;
}
__device__ __forceinline__ void pl32_swap(unsigned &a, unsigned &b) {
    asm volatile("v_permlane32_swap_b32 %0, %1" : "+v"(a), "+v"(b));
}

// ---------------------------------------------------------------------------
// fp32 -> bf16 vectorized convert (8 elems/thread)
// ---------------------------------------------------------------------------
__global__ __launch_bounds__(256) void cvt_bf16(
    const float* __restrict__ in, ushort* __restrict__ out, int n)
{
    const int i = (blockIdx.x * 256 + threadIdx.x) * 8;
    if (i + 8 <= n) {
        const f32x4 a = *(const f32x4*)(in + i);
        const f32x4 b = *(const f32x4*)(in + i + 4);
        union { ushort u[8]; i32x4 w; } p;
        #pragma unroll
        for (int j = 0; j < 4; ++j) { p.u[j] = f2bf(a[j]); p.u[4 + j] = f2bf(b[j]); }
        *(i32x4*)(out + i) = p.w;
    }
}

// ---------------------------------------------------------------------------
// 3x QKV weights fp32 -> bf16, concat into wbf[3][512*512]
// (consumed by gemm_qkv3 BEFORE attn overwrites the ab region it lives in)
// ---------------------------------------------------------------------------
__global__ __launch_bounds__(256) void cvt_w3(
    const float* __restrict__ w0, const float* __restrict__ w1,
    const float* __restrict__ w2, ushort* __restrict__ out)
{
    const int i = (blockIdx.x * 256 + threadIdx.x) * 8;   // < 3*262144
    const int w = i >> 18, off = i & 262143;
    const float* src = (w == 0) ? w0 : ((w == 1) ? w1 : w2);
    const f32x4 a = *(const f32x4*)(src + off);
    const f32x4 b = *(const f32x4*)(src + off + 4);
    union { ushort u[8]; i32x4 v; } p;
    #pragma unroll
    for (int j = 0; j < 4; ++j) { p.u[j] = f2bf(a[j]); p.u[4 + j] = f2bf(b[j]); }
    *(i32x4*)(out + i) = p.v;
}

// ---------------------------------------------------------------------------
// Fused QKV GEMM (pipelined staging): C = A(bf16) * Wbf(bf16)^T * scale
// blockIdx.y: (y>>2) selects {Wq,Wk,Wv}; (y&3) is the 128-col n-tile.
// q,k -> bf16 head-interleaved [b,h,t,64]; v -> TRANSPOSED [b,h,d,2048]
// ---------------------------------------------------------------------------
__global__ __launch_bounds__(256) void gemm_qkv3(
    const ushort* __restrict__ A, const ushort* __restrict__ Wbf,
    float qscale, ushort* __restrict__ qb, ushort* __restrict__ kb,
    ushort* __restrict__ vb)
{
    __shared__ ushort lA[128][40];
    __shared__ ushort lB[128][40];
    const int wsel = blockIdx.y >> 2;
    const int n0 = (blockIdx.y & 3) * 128;
    const ushort* W = Wbf + wsel * 262144;
    ushort* out = (wsel == 0) ? qb : ((wsel == 1) ? kb : vb);
    const float scale = (wsel == 0) ? qscale : 1.0f;

    const int m0 = blockIdx.x * 128;
    const int tid  = threadIdx.x;
    const int lane = tid & 63;
    const int wave = tid >> 6;
    const int wr = (wave >> 1) * 64, wc = (wave & 1) * 64;
    const int frow = lane & 15, fk = (lane >> 4) * 8;
    const int sr = tid >> 1, scc = (tid & 1) * 16;

    f32x4 acc[4][4] = {};
    i32x4 va0, va1, vb0, vb1;
    auto load = [&](int k0) {
        const ushort* pa = A + (m0 + sr) * 512 + k0 + scc;
        va0 = *(const i32x4*)(pa);
        va1 = *(const i32x4*)(pa + 8);
        const ushort* pb = W + (n0 + sr) * 512 + k0 + scc;
        vb0 = *(const i32x4*)(pb);
        vb1 = *(const i32x4*)(pb + 8);
    };

    load(0);
    for (int t = 0; t < 16; ++t) {
        __syncthreads();                       // prior step's LDS reads done
        *(i32x4*)&lA[sr][scc]     = va0;
        *(i32x4*)&lA[sr][scc + 8] = va1;
        *(i32x4*)&lB[sr][scc]     = vb0;
        *(i32x4*)&lB[sr][scc + 8] = vb1;
        if (t + 1 < 16) load((t + 1) * 32);    // next step hides under compute
        __syncthreads();

        bf16x8 af[4], bg[4];
        #pragma unroll
        for (int m = 0; m < 4; ++m) af[m] = *(const bf16x8*)&lA[wr + m * 16 + frow][fk];
        #pragma unroll
        for (int n = 0; n < 4; ++n) bg[n] = *(const bf16x8*)&lB[wc + n * 16 + frow][fk];
        #pragma unroll
        for (int m = 0; m < 4; ++m)
            #pragma unroll
            for (int n = 0; n < 4; ++n)
                acc[m][n] = MFMA_16x16x32(af[m], bg[n], acc[m][n]);
    }

    const int rbase = (lane >> 4) * 4;
    const int ccol  = lane & 15;
    if (wsel == 2) {
        // V transposed: vt[((b*8+h)*64 + d)*2048 + t], pack 4 consecutive t
        #pragma unroll
        for (int m = 0; m < 4; ++m)
            #pragma unroll
            for (int n = 0; n < 4; ++n) {
                const int col = n0 + wc + n * 16 + ccol;
                const int row0 = m0 + wr + m * 16 + rbase;
                unsigned long long u = 0;
                #pragma unroll
                for (int r = 0; r < 4; ++r)
                    u |= ((unsigned long long)f2bf(acc[m][n][r])) << (16 * r);
                const size_t idx = ((size_t)((row0 >> 11) * 8 + (col >> 6)) * 64
                                    + (col & 63)) * 2048 + (row0 & 2047);
                *(unsigned long long*)(out + idx) = u;
            }
    } else {
        #pragma unroll
        for (int m = 0; m < 4; ++m)
            #pragma unroll
            for (int n = 0; n < 4; ++n) {
                const int col = n0 + wc + n * 16 + ccol;
                #pragma unroll
                for (int r = 0; r < 4; ++r) {
                    const int row = m0 + wr + m * 16 + rbase + r;
                    out[(((row >> 11) * 8 + (col >> 6)) * 2048 + (row & 2047)) * 64 + (col & 63)]
                        = f2bf(acc[m][n][r] * scale);
                }
            }
    }
}

// ---------------------------------------------------------------------------
// Output GEMM (pipelined staging): C[M,512](fp32) = A(bf16, head-il) * Wp^T + bp
// (Wp read as fp32 directly — R9-proven; Wp-bf16 parking has no safe lifetime)
// ---------------------------------------------------------------------------
__global__ __launch_bounds__(256) void gemm_out(
    const ushort* __restrict__ A, const float* __restrict__ W,
    const float* __restrict__ bias, float* __restrict__ out)
{
    __shared__ ushort lA[128][40];
    __shared__ ushort lB[128][40];
    const int m0 = blockIdx.x * 128;
    const int n0 = blockIdx.y * 128;
    const int tid  = threadIdx.x;
    const int lane = tid & 63;
    const int wave = tid >> 6;
    const int wr = (wave >> 1) * 64, wc = (wave & 1) * 64;
    const int frow = lane & 15, fk = (lane >> 4) * 8;
    const int sr = tid >> 1, scc = (tid & 1) * 16;

    f32x4 acc[4][4] = {};
    i32x4 va0, va1;
    f32x4 b0, b1, b2, b3;
    auto load = [&](int k0) {
        const int row = m0 + sr, c = k0 + scc;
        const ushort* pa = A + ((((row >> 11) * 8 + (c >> 6)) * 2048 + (row & 2047)) * 64 + (c & 63));
        va0 = *(const i32x4*)(pa);
        va1 = *(const i32x4*)(pa + 8);
        const float* pb = W + (n0 + sr) * 512 + k0 + scc;
        b0 = *(const f32x4*)(pb);
        b1 = *(const f32x4*)(pb + 4);
        b2 = *(const f32x4*)(pb + 8);
        b3 = *(const f32x4*)(pb + 12);
    };

    load(0);
    for (int t = 0; t < 16; ++t) {
        union { ushort u[16]; i32x4 w[2]; } pB;
        #pragma unroll
        for (int j = 0; j < 4; ++j) {
            pB.u[j]      = f2bf(b0[j]);  pB.u[4 + j]  = f2bf(b1[j]);
            pB.u[8 + j]  = f2bf(b2[j]);  pB.u[12 + j] = f2bf(b3[j]);
        }
        __syncthreads();
        *(i32x4*)&lA[sr][scc]     = va0;
        *(i32x4*)&lA[sr][scc + 8] = va1;
        *(i32x4*)&lB[sr][scc]     = pB.w[0];
        *(i32x4*)&lB[sr][scc + 8] = pB.w[1];
        if (t + 1 < 16) load((t + 1) * 32);
        __syncthreads();

        bf16x8 af[4], bg[4];
        #pragma unroll
        for (int m = 0; m < 4; ++m) af[m] = *(const bf16x8*)&lA[wr + m * 16 + frow][fk];
        #pragma unroll
        for (int n = 0; n < 4; ++n) bg[n] = *(const bf16x8*)&lB[wc + n * 16 + frow][fk];
        #pragma unroll
        for (int m = 0; m < 4; ++m)
            #pragma unroll
            for (int n = 0; n < 4; ++n)
                acc[m][n] = MFMA_16x16x32(af[m], bg[n], acc[m][n]);
    }

    const int rbase = (lane >> 4) * 4;
    const int ccol  = lane & 15;
    #pragma unroll
    for (int m = 0; m < 4; ++m)
        #pragma unroll
        for (int n = 0; n < 4; ++n) {
            const int col = n0 + wc + n * 16 + ccol;
            const float bv = bias[col];
            #pragma unroll
            for (int r = 0; r < 4; ++r) {
                const int row = m0 + wr + m * 16 + rbase + r;
                out[row * 512 + col] = acc[m][n][r] + bv;
            }
        }
}

// ---------------------------------------------------------------------------
// Causal flash attention (R7/R9 winning config + T5 setprio): 4 waves x 128
// q-rows per block, K/V shared via LDS double-buffer (XOR-swizzled), per-wave
// swapped-QK^T 32x32 in-register softmax. q,k: [bh][t][64]; vt: [bh][d][2048].
// ---------------------------------------------------------------------------
__global__ __launch_bounds__(256, 2) void attn_kernel(
    const ushort* __restrict__ q, const ushort* __restrict__ k,
    const ushort* __restrict__ vt, ushort* __restrict__ att)
{
    __shared__ ushort lK[2][64][64];    // [buf][s_local][d], XOR-swizzled groups
    __shared__ ushort lV[2][64][64];    // [buf][d][s_local], XOR-swizzled groups

    const int NB   = (int)(gridDim.x * gridDim.y);
    const int NH   = NB >> 4;            // number of bh slices (16 q-tiles)
    const int half = NB >> 1;
    const int n    = (int)(blockIdx.y * gridDim.x + blockIdx.x);
    const int r    = (n < half) ? n : (NB - 1 - (n - half));
    const int qt0  = (15 - r / NH) * 128;    // heavy-first
    const int bh   = r % NH;

    const ushort* Q  = q  + (size_t)bh * 2048 * 64;
    const ushort* K  = k  + (size_t)bh * 2048 * 64;
    const ushort* VT = vt + (size_t)bh * 2048 * 64;
    ushort* O = att + (size_t)bh * 2048 * 64;

    const int tid = threadIdx.x;
    const int wv  = tid >> 6;
    const int l   = tid & 63;
    const int ql  = l & 31;
    const int hi  = l >> 5;
    const int wrow0 = qt0 + wv * 32;     // wave's first q-row
    const int qrow  = wrow0 + ql;
    const int wmax  = wrow0 + 31;
    const int qkey  = ql & 7;
    const float LOG2E = 1.44269504088896f;

    // staging map: thread -> (row, 2 groups of 8 elems)
    const int srow = tid >> 2;
    const int sg   = (tid & 3) * 2;
    const int skey = srow & 7;

    bf16x8 aq[4];
    #pragma unroll
    for (int kk = 0; kk < 4; ++kk)
        aq[kk] = *(const bf16x8*)(Q + (size_t)qrow * 64 + kk * 16 + hi * 8);

    f32x16 o0 = {}, o1 = {};
    float mrun = -30000.0f, lrun = 0.0f;
    const int nt = qt0 / 64 + 2;

    i32x4 kr0, kr1, vr0, vr1;            // staging registers
    auto loadG = [&](int s0) {
        const ushort* kp = K + (size_t)(s0 + srow) * 64 + (tid & 3) * 16;
        kr0 = *(const i32x4*)(kp);
        kr1 = *(const i32x4*)(kp + 8);
        const ushort* vp = VT + (size_t)srow * 2048 + s0 + (tid & 3) * 16;
        vr0 = *(const i32x4*)(vp);
        vr1 = *(const i32x4*)(vp + 8);
    };
    auto writeL = [&](int b) {
        *(i32x4*)&lK[b][srow][((sg    ) ^ skey) * 8] = kr0;
        *(i32x4*)&lK[b][srow][((sg + 1) ^ skey) * 8] = kr1;
        *(i32x4*)&lV[b][srow][((sg    ) ^ skey) * 8] = vr0;
        *(i32x4*)&lV[b][srow][((sg + 1) ^ skey) * 8] = vr1;
    };

    loadG(0);
    writeL(0);
    if (nt > 1) loadG(64);               // tile 1 in regs across iter 0

    for (int t = 0; t < nt; ++t) {
        const int p  = t & 1;
        const int s0 = t * 64;
        __syncthreads();                  // buf[p] visible; buf[p^1] drained
        if (t + 1 < nt) writeL(p ^ 1);    // regs (tile t+1) -> LDS
        if (t + 2 < nt) loadG(s0 + 128);  // issue tile t+2, lands next iter

        if (s0 > wmax) continue;          // fully-masked tile for this wave

        // S^T = K * Q^T from LDS (swizzled reads)
        f32x16 sa = {}, sb = {};
        __builtin_amdgcn_s_setprio(1);
        #pragma unroll
        for (int kk = 0; kk < 4; ++kk) {
            const bf16x8 kb0 = *(const bf16x8*)&lK[p][ql]     [((2 * kk + hi) ^ qkey) * 8];
            const bf16x8 kb1 = *(const bf16x8*)&lK[p][32 + ql][((2 * kk + hi) ^ qkey) * 8];
            sa = MFMA32(kb0, aq[kk], sa);
            sb = MFMA32(kb1, aq[kk], sb);
        }
        __builtin_amdgcn_s_setprio(0);

        if (s0 + 63 > wrow0) {            // tile intersects this wave's diagonal
            #pragma unroll
            for (int rr = 0; rr < 16; ++rr) {
                const int cr = (rr & 3) + 8 * (rr >> 2) + 4 * hi;
                if (s0 + cr > qrow)      sa[rr] = -30000.0f;
                if (s0 + 32 + cr > qrow) sb[rr] = -30000.0f;
            }
        }

        // row max (lane-local rows): 31 fmax + 1 cross-half shuffle
        float pmax = sa[0];
        #pragma unroll
        for (int rr = 1; rr < 16; ++rr) pmax = fmaxf(pmax, sa[rr]);
        #pragma unroll
        for (int rr = 0; rr < 16; ++rr) pmax = fmaxf(pmax, sb[rr]);
        pmax = fmaxf(pmax, __shfl_xor(pmax, 32));

        // defer-max (T13)
        if (__any(pmax > mrun + 8.0f)) {
            const float mnew  = fmaxf(mrun, pmax);
            const float alpha = exp2f((mrun - mnew) * LOG2E);
            mrun = mnew;
            lrun *= alpha;
            #pragma unroll
            for (int rr = 0; rr < 16; ++rr) {
                const float ar = __shfl(alpha, (rr & 3) + 8 * (rr >> 2) + 4 * hi);
                o0[rr] *= ar; o1[rr] *= ar;
            }
        }

        const float mb = mrun * LOG2E;
        float ps = 0.0f;
        #pragma unroll
        for (int rr = 0; rr < 16; ++rr) {
            sa[rr] = exp2f(fmaf(sa[rr], LOG2E, -mb));
            sb[rr] = exp2f(fmaf(sb[rr], LOG2E, -mb));
            ps += sa[rr] + sb[rr];
        }
        ps += __shfl_xor(ps, 32);
        lrun += ps;

        // P -> PV A-fragments (T12)
        unsigned paw[4][4];
        #pragma unroll
        for (int ks = 0; ks < 4; ++ks) {
            const int e = 2 * ks, f = 2 * ks + 1;
            const int ra = 4 * (e & 3), rb = 4 * (f & 3);
            unsigned A0, A1, B0, B1;
            if (e >> 2) { A0 = pk_bf16(sb[ra], sb[ra + 1]); A1 = pk_bf16(sb[ra + 2], sb[ra + 3]); }
            else        { A0 = pk_bf16(sa[ra], sa[ra + 1]); A1 = pk_bf16(sa[ra + 2], sa[ra + 3]); }
            if (f >> 2) { B0 = pk_bf16(sb[rb], sb[rb + 1]); B1 = pk_bf16(sb[rb + 2], sb[rb + 3]); }
            else        { B0 = pk_bf16(sa[rb], sa[rb + 1]); B1 = pk_bf16(sa[rb + 2], sa[rb + 3]); }
            pl32_swap(A0, B0);
            pl32_swap(A1, B1);
            paw[ks][0] = A0; paw[ks][1] = A1; paw[ks][2] = B0; paw[ks][3] = B1;
        }

        // O += P * V from LDS V^T tile (swizzled reads)
        __builtin_amdgcn_s_setprio(1);
        #pragma unroll
        for (int ks = 0; ks < 4; ++ks) {
            union { unsigned w[4]; bf16x8 v; } u;
            u.w[0] = paw[ks][0]; u.w[1] = paw[ks][1];
            u.w[2] = paw[ks][2]; u.w[3] = paw[ks][3];
            const bf16x8 v0 = *(const bf16x8*)&lV[p][ql]     [((2 * ks + hi) ^ qkey) * 8];
            const bf16x8 v1 = *(const bf16x8*)&lV[p][32 + ql][((2 * ks + hi) ^ qkey) * 8];
            o0 = MFMA32(u.v, v0, o0);
            o1 = MFMA32(u.v, v1, o1);
        }
        __builtin_amdgcn_s_setprio(0);
    }

    // epilogue
    const float linv = 1.0f / fmaxf(lrun, 1e-30f);
    #pragma unroll
    for (int rr = 0; rr < 16; ++rr) {
        const int cr = (rr & 3) + 8 * (rr >> 2) + 4 * hi;
        const float li = __shfl(linv, cr);
        const int row = wrow0 + cr;
        O[(size_t)row * 64 + ql]      = f2bf(o0[rr] * li);
        O[(size_t)row * 64 + 32 + ql] = f2bf(o1[rr] * li);
    }
}

extern "C" void kernel_launch(void* const* d_in, const int* in_sizes, int n_in,
                              void* d_out, int out_size, void* d_ws, size_t ws_size,
                              hipStream_t stream) {
    const float* x  = (const float*)d_in[0];   // x_q  [4,2048,512] fp32
    const float* Wq = (const float*)d_in[1];   // [8,64,512] fp32
    const float* Wk = (const float*)d_in[2];
    const float* Wv = (const float*)d_in[3];
    const float* Wp = (const float*)d_in[4];   // [512,512] fp32
    const float* bp = (const float*)d_in[5];   // [512] fp32
    float* out = (float*)d_out;                // [4,2048,512] fp32

    const size_t NEL  = 4u * 8u * 2048u * 64u;   // 4,194,304 (all batches)
    const size_t NELB = 8u * 2048u * 64u;        // 1,048,576 (one batch)
    const float qscale = 0.04419417382415922f;   // 512^-0.5 folded into q

    if (ws_size >= 3u * NEL * sizeof(ushort)) {
        // d_out bytes: [xbf (bf16 x)][qb (bf16 q)] — final GEMM overwrites.
        // wbf (QKV bf16 weights) parks at ab; consumed by gemm_qkv3 BEFORE
        // attn overwrites ab. Wp stays fp32 (no safe parking past attn).
        ushort* xbf = (ushort*)d_out;
        ushort* qb  = xbf + NEL;
        ushort* kb  = (ushort*)d_ws;
        ushort* vb  = kb + NEL;                  // holds VT [b,h,d,2048]
        ushort* ab  = vb + NEL;
        ushort* wbf = ab;                        // 3*262144 ushorts = 1.5 MB
        hipLaunchKernelGGL(cvt_bf16, dim3((int)(NEL / (256 * 8))), dim3(256), 0, stream,
                           x, xbf, (int)NEL);
        hipLaunchKernelGGL(cvt_w3, dim3(384), dim3(256), 0, stream, Wq, Wk, Wv, wbf);
        hipLaunchKernelGGL(gemm_qkv3, dim3(64, 12), dim3(256), 0, stream,
                           xbf, wbf, qscale, qb, kb, vb);
        hipLaunchKernelGGL(attn_kernel, dim3(16, 32), dim3(256), 0, stream, qb, kb, vb, ab);
        hipLaunchKernelGGL(gemm_out, dim3(64, 4), dim3(256), 0, stream, ab, Wp, bp, out);
    } else {
        // per-batch fallback: ws need = 3 * NELB * 2 = 6.3 MB
        ushort* kb = (ushort*)d_ws;
        ushort* vb = kb + NELB;
        ushort* ab = vb + NELB;
        ushort* wbf = ab;                        // 1.5 MB slice
        for (int b = 0; b < 4; ++b) {
            const float* xb = x + (size_t)b * 2048u * 512u;
            float* ob = out + (size_t)b * 2048u * 512u;
            ushort* xbf = (ushort*)ob;           // batch slice: [xbf][qb]
            ushort* qb  = xbf + NELB;
            hipLaunchKernelGGL(cvt_bf16, dim3((int)(NELB / (256 * 8))), dim3(256), 0, stream,
                               xb, xbf, (int)NELB);
            hipLaunchKernelGGL(cvt_w3, dim3(384), dim3(256), 0, stream, Wq, Wk, Wv, wbf);
            hipLaunchKernelGGL(gemm_qkv3, dim3(16, 12), dim3(256), 0, stream,
                               xbf, wbf, qscale, qb, kb, vb);
            hipLaunchKernelGGL(attn_kernel, dim3(16, 8), dim3(256), 0, stream, qb, kb, vb, ab);
            hipLaunchKernelGGL(gemm_out, dim3(16, 4), dim3(256), 0, stream, ab, Wp, bp, ob);
        }
    }
}

// Round 13
// 104.108 us; speedup vs baseline: 1.3290x; 1.0362x over previous
//
#include <hip/hip_runtime.h>
#include <hip/hip_bf16.h>

using bf16x8 = __attribute__((ext_vector_type(8))) __bf16;
using f32x4  = __attribute__((ext_vector_type(4))) float;
using f32x16 = __attribute__((ext_vector_type(16))) float;
using i32x4  = __attribute__((ext_vector_type(4))) int;

#define MFMA_16x16x32(a, b, c) __builtin_amdgcn_mfma_f32_16x16x32_bf16((a), (b), (c), 0, 0, 0)
#define MFMA32(a, b, c)        __builtin_amdgcn_mfma_f32_32x32x16_bf16((a), (b), (c), 0, 0, 0)

// async global->LDS, 16 B per lane; LDS dest = wave-uniform base + lane*16
#define GLOAD16(g, l)                                                         \
    __builtin_amdgcn_global_load_lds(                                         \
        (const __attribute__((address_space(1))) unsigned int*)(g),           \
        (__attribute__((address_space(3))) unsigned int*)(l), 16, 0, 0)

__device__ __forceinline__ ushort f2bf(float f) {
    return __builtin_bit_cast(ushort, (__bf16)f);
}
__device__ __forceinline__ unsigned pk_bf16(float lo, float hi) {
    unsigned r;
    asm volatile("v_cvt_pk_bf16_f32 %0, %1, %2" : "=v"(r) : "v"(lo), "v"(hi));
    return r;
}
__device__ __forceinline__ void pl32_swap(unsigned &a, unsigned &b) {
    asm volatile("v_permlane32_swap_b32 %0, %1" : "+v"(a), "+v"(b));
}

// ---------------------------------------------------------------------------
// fp32 -> bf16 vectorized convert (8 elems/thread)
// ---------------------------------------------------------------------------
__global__ __launch_bounds__(256) void cvt_bf16(
    const float* __restrict__ in, ushort* __restrict__ out, int n)
{
    const int i = (blockIdx.x * 256 + threadIdx.x) * 8;
    if (i + 8 <= n) {
        const f32x4 a = *(const f32x4*)(in + i);
        const f32x4 b = *(const f32x4*)(in + i + 4);
        union { ushort u[8]; i32x4 w; } p;
        #pragma unroll
        for (int j = 0; j < 4; ++j) { p.u[j] = f2bf(a[j]); p.u[4 + j] = f2bf(b[j]); }
        *(i32x4*)(out + i) = p.w;
    }
}

// ---------------------------------------------------------------------------
// 3x QKV weights fp32 -> bf16, concat into wbf[3][512*512]
// ---------------------------------------------------------------------------
__global__ __launch_bounds__(256) void cvt_w3(
    const float* __restrict__ w0, const float* __restrict__ w1,
    const float* __restrict__ w2, ushort* __restrict__ out)
{
    const int i = (blockIdx.x * 256 + threadIdx.x) * 8;   // < 3*262144
    const int w = i >> 18, off = i & 262143;
    const float* src = (w == 0) ? w0 : ((w == 1) ? w1 : w2);
    const f32x4 a = *(const f32x4*)(src + off);
    const f32x4 b = *(const f32x4*)(src + off + 4);
    union { ushort u[8]; i32x4 v; } p;
    #pragma unroll
    for (int j = 0; j < 4; ++j) { p.u[j] = f2bf(a[j]); p.u[4 + j] = f2bf(b[j]); }
    *(i32x4*)(out + i) = p.v;
}

// ---------------------------------------------------------------------------
// Fused QKV GEMM, global_load_lds staging (linear LDS dbuf + pre-swizzled
// source; read swizzle key = (row>>1)&3 -> <=2-way banks).
// blockIdx.y: (y>>2) selects {Wq,Wk,Wv}; (y&3) is the 128-col n-tile.
// q,k -> bf16 head-interleaved [b,h,t,64]; v -> TRANSPOSED [b,h,d,2048]
// ---------------------------------------------------------------------------
__global__ __launch_bounds__(256) void gemm_qkv3(
    const ushort* __restrict__ A, const ushort* __restrict__ Wbf,
    float qscale, ushort* __restrict__ qb, ushort* __restrict__ kb,
    ushort* __restrict__ vb)
{
    __shared__ ushort lA[2][128][32];
    __shared__ ushort lB[2][128][32];
    const int wsel = blockIdx.y >> 2;
    const int n0 = (blockIdx.y & 3) * 128;
    const ushort* W = Wbf + wsel * 262144;
    ushort* out = (wsel == 0) ? qb : ((wsel == 1) ? kb : vb);
    const float scale = (wsel == 0) ? qscale : 1.0f;

    const int m0 = blockIdx.x * 128;
    const int tid  = threadIdx.x;
    const int lane = tid & 63;
    const int wave = tid >> 6;
    const int wr = (wave >> 1) * 64, wc = (wave & 1) * 64;
    const int frow = lane & 15;
    // physical group for logical group (lane>>4) under key (row>>1)&3=(lane>>1)&3
    const int fkp  = (((lane >> 4) ^ ((lane >> 1) & 3))) * 8;

    // staging: instruction (wave,i) fills rows [(wave*2+i)*16, +16), lane ->
    // row += lane>>2, phys group lane&3; source col pre-swizzled by (lane>>3)&3
    const int srw  = lane >> 2;
    const int scol = ((lane & 3) ^ ((lane >> 3) & 3)) * 8;

    f32x4 acc[4][4] = {};
    auto stage = [&](int k0, int b) {
        #pragma unroll
        for (int i = 0; i < 2; ++i) {
            const int rb = (wave * 2 + i) * 16;
            GLOAD16(A + (size_t)(m0 + rb + srw) * 512 + k0 + scol, &lA[b][rb][0]);
            GLOAD16(W + (size_t)(n0 + rb + srw) * 512 + k0 + scol, &lB[b][rb][0]);
        }
    };

    stage(0, 0);
    for (int t = 0; t < 16; ++t) {
        const int p = t & 1;
        __syncthreads();                       // vmcnt drain: buf[p] ready;
                                               // prior reads of buf[p^1] done
        if (t + 1 < 16) stage((t + 1) * 32, p ^ 1);

        bf16x8 af[4], bg[4];
        #pragma unroll
        for (int m = 0; m < 4; ++m) af[m] = *(const bf16x8*)&lA[p][wr + m * 16 + frow][fkp];
        #pragma unroll
        for (int n = 0; n < 4; ++n) bg[n] = *(const bf16x8*)&lB[p][wc + n * 16 + frow][fkp];
        #pragma unroll
        for (int m = 0; m < 4; ++m)
            #pragma unroll
            for (int n = 0; n < 4; ++n)
                acc[m][n] = MFMA_16x16x32(af[m], bg[n], acc[m][n]);
    }

    const int rbase = (lane >> 4) * 4;
    const int ccol  = lane & 15;
    if (wsel == 2) {
        // V transposed: vt[((b*8+h)*64 + d)*2048 + t], pack 4 consecutive t
        #pragma unroll
        for (int m = 0; m < 4; ++m)
            #pragma unroll
            for (int n = 0; n < 4; ++n) {
                const int col = n0 + wc + n * 16 + ccol;
                const int row0 = m0 + wr + m * 16 + rbase;
                unsigned long long u = 0;
                #pragma unroll
                for (int r = 0; r < 4; ++r)
                    u |= ((unsigned long long)f2bf(acc[m][n][r])) << (16 * r);
                const size_t idx = ((size_t)((row0 >> 11) * 8 + (col >> 6)) * 64
                                    + (col & 63)) * 2048 + (row0 & 2047);
                *(unsigned long long*)(out + idx) = u;
            }
    } else {
        #pragma unroll
        for (int m = 0; m < 4; ++m)
            #pragma unroll
            for (int n = 0; n < 4; ++n) {
                const int col = n0 + wc + n * 16 + ccol;
                #pragma unroll
                for (int r = 0; r < 4; ++r) {
                    const int row = m0 + wr + m * 16 + rbase + r;
                    out[(((row >> 11) * 8 + (col >> 6)) * 2048 + (row & 2047)) * 64 + (col & 63)]
                        = f2bf(acc[m][n][r] * scale);
                }
            }
    }
}

// ---------------------------------------------------------------------------
// Output GEMM (unchanged control): C[M,512](fp32) = A(bf16, head-il)*Wp^T + bp
// ---------------------------------------------------------------------------
__global__ __launch_bounds__(256) void gemm_out(
    const ushort* __restrict__ A, const float* __restrict__ W,
    const float* __restrict__ bias, float* __restrict__ out)
{
    __shared__ ushort lA[128][40];
    __shared__ ushort lB[128][40];
    const int m0 = blockIdx.x * 128;
    const int n0 = blockIdx.y * 128;
    const int tid  = threadIdx.x;
    const int lane = tid & 63;
    const int wave = tid >> 6;
    const int wr = (wave >> 1) * 64, wc = (wave & 1) * 64;
    const int frow = lane & 15, fk = (lane >> 4) * 8;
    const int sr = tid >> 1, scc = (tid & 1) * 16;

    f32x4 acc[4][4] = {};
    i32x4 va0, va1;
    f32x4 b0, b1, b2, b3;
    auto load = [&](int k0) {
        const int row = m0 + sr, c = k0 + scc;
        const ushort* pa = A + ((((row >> 11) * 8 + (c >> 6)) * 2048 + (row & 2047)) * 64 + (c & 63));
        va0 = *(const i32x4*)(pa);
        va1 = *(const i32x4*)(pa + 8);
        const float* pb = W + (n0 + sr) * 512 + k0 + scc;
        b0 = *(const f32x4*)(pb);
        b1 = *(const f32x4*)(pb + 4);
        b2 = *(const f32x4*)(pb + 8);
        b3 = *(const f32x4*)(pb + 12);
    };

    load(0);
    for (int t = 0; t < 16; ++t) {
        union { ushort u[16]; i32x4 w[2]; } pB;
        #pragma unroll
        for (int j = 0; j < 4; ++j) {
            pB.u[j]      = f2bf(b0[j]);  pB.u[4 + j]  = f2bf(b1[j]);
            pB.u[8 + j]  = f2bf(b2[j]);  pB.u[12 + j] = f2bf(b3[j]);
        }
        __syncthreads();
        *(i32x4*)&lA[sr][scc]     = va0;
        *(i32x4*)&lA[sr][scc + 8] = va1;
        *(i32x4*)&lB[sr][scc]     = pB.w[0];
        *(i32x4*)&lB[sr][scc + 8] = pB.w[1];
        if (t + 1 < 16) load((t + 1) * 32);
        __syncthreads();

        bf16x8 af[4], bg[4];
        #pragma unroll
        for (int m = 0; m < 4; ++m) af[m] = *(const bf16x8*)&lA[wr + m * 16 + frow][fk];
        #pragma unroll
        for (int n = 0; n < 4; ++n) bg[n] = *(const bf16x8*)&lB[wc + n * 16 + frow][fk];
        #pragma unroll
        for (int m = 0; m < 4; ++m)
            #pragma unroll
            for (int n = 0; n < 4; ++n)
                acc[m][n] = MFMA_16x16x32(af[m], bg[n], acc[m][n]);
    }

    const int rbase = (lane >> 4) * 4;
    const int ccol  = lane & 15;
    #pragma unroll
    for (int m = 0; m < 4; ++m)
        #pragma unroll
        for (int n = 0; n < 4; ++n) {
            const int col = n0 + wc + n * 16 + ccol;
            const float bv = bias[col];
            #pragma unroll
            for (int r = 0; r < 4; ++r) {
                const int row = m0 + wr + m * 16 + rbase + r;
                out[row * 512 + col] = acc[m][n][r] + bv;
            }
        }
}

// ---------------------------------------------------------------------------
// Causal flash attention (R9 winning config + tree reductions, no setprio):
// 4 waves x 128 q-rows, K/V LDS double-buffer (XOR-swizzled), per-wave
// swapped-QK^T 32x32 in-register softmax. q,k: [bh][t][64]; vt: [bh][d][2048].
// ---------------------------------------------------------------------------
__global__ __launch_bounds__(256, 2) void attn_kernel(
    const ushort* __restrict__ q, const ushort* __restrict__ k,
    const ushort* __restrict__ vt, ushort* __restrict__ att)
{
    __shared__ ushort lK[2][64][64];
    __shared__ ushort lV[2][64][64];

    const int NB   = (int)(gridDim.x * gridDim.y);
    const int NH   = NB >> 4;
    const int half = NB >> 1;
    const int n    = (int)(blockIdx.y * gridDim.x + blockIdx.x);
    const int r    = (n < half) ? n : (NB - 1 - (n - half));
    const int qt0  = (15 - r / NH) * 128;    // heavy-first
    const int bh   = r % NH;

    const ushort* Q  = q  + (size_t)bh * 2048 * 64;
    const ushort* K  = k  + (size_t)bh * 2048 * 64;
    const ushort* VT = vt + (size_t)bh * 2048 * 64;
    ushort* O = att + (size_t)bh * 2048 * 64;

    const int tid = threadIdx.x;
    const int wv  = tid >> 6;
    const int l   = tid & 63;
    const int ql  = l & 31;
    const int hi  = l >> 5;
    const int wrow0 = qt0 + wv * 32;
    const int qrow  = wrow0 + ql;
    const int wmax  = wrow0 + 31;
    const int qkey  = ql & 7;
    const float LOG2E = 1.44269504088896f;

    const int srow = tid >> 2;
    const int sg   = (tid & 3) * 2;
    const int skey = srow & 7;

    bf16x8 aq[4];
    #pragma unroll
    for (int kk = 0; kk < 4; ++kk)
        aq[kk] = *(const bf16x8*)(Q + (size_t)qrow * 64 + kk * 16 + hi * 8);

    f32x16 o0 = {}, o1 = {};
    float mrun = -30000.0f, lrun = 0.0f;
    const int nt = qt0 / 64 + 2;

    i32x4 kr0, kr1, vr0, vr1;
    auto loadG = [&](int s0) {
        const ushort* kp = K + (size_t)(s0 + srow) * 64 + (tid & 3) * 16;
        kr0 = *(const i32x4*)(kp);
        kr1 = *(const i32x4*)(kp + 8);
        const ushort* vp = VT + (size_t)srow * 2048 + s0 + (tid & 3) * 16;
        vr0 = *(const i32x4*)(vp);
        vr1 = *(const i32x4*)(vp + 8);
    };
    auto writeL = [&](int b) {
        *(i32x4*)&lK[b][srow][((sg    ) ^ skey) * 8] = kr0;
        *(i32x4*)&lK[b][srow][((sg + 1) ^ skey) * 8] = kr1;
        *(i32x4*)&lV[b][srow][((sg    ) ^ skey) * 8] = vr0;
        *(i32x4*)&lV[b][srow][((sg + 1) ^ skey) * 8] = vr1;
    };

    loadG(0);
    writeL(0);
    if (nt > 1) loadG(64);

    for (int t = 0; t < nt; ++t) {
        const int p  = t & 1;
        const int s0 = t * 64;
        __syncthreads();
        if (t + 1 < nt) writeL(p ^ 1);
        if (t + 2 < nt) loadG(s0 + 128);

        if (s0 > wmax) continue;

        // S^T = K * Q^T from LDS (swizzled reads)
        f32x16 sa = {}, sb = {};
        #pragma unroll
        for (int kk = 0; kk < 4; ++kk) {
            const bf16x8 kb0 = *(const bf16x8*)&lK[p][ql]     [((2 * kk + hi) ^ qkey) * 8];
            const bf16x8 kb1 = *(const bf16x8*)&lK[p][32 + ql][((2 * kk + hi) ^ qkey) * 8];
            sa = MFMA32(kb0, aq[kk], sa);
            sb = MFMA32(kb1, aq[kk], sb);
        }

        if (s0 + 63 > wrow0) {
            #pragma unroll
            for (int rr = 0; rr < 16; ++rr) {
                const int cr = (rr & 3) + 8 * (rr >> 2) + 4 * hi;
                if (s0 + cr > qrow)      sa[rr] = -30000.0f;
                if (s0 + 32 + cr > qrow) sb[rr] = -30000.0f;
            }
        }

        // row max: depth-5 tree (was 31-deep serial chain)
        float tm[16];
        #pragma unroll
        for (int rr = 0; rr < 16; ++rr) tm[rr] = fmaxf(sa[rr], sb[rr]);
        #pragma unroll
        for (int s = 8; s > 0; s >>= 1)
            #pragma unroll
            for (int rr = 0; rr < s; ++rr) tm[rr] = fmaxf(tm[rr], tm[rr + s]);
        float pmax = fmaxf(tm[0], __shfl_xor(tm[0], 32));

        // defer-max (T13)
        if (__any(pmax > mrun + 8.0f)) {
            const float mnew  = fmaxf(mrun, pmax);
            const float alpha = exp2f((mrun - mnew) * LOG2E);
            mrun = mnew;
            lrun *= alpha;
            #pragma unroll
            for (int rr = 0; rr < 16; ++rr) {
                const float ar = __shfl(alpha, (rr & 3) + 8 * (rr >> 2) + 4 * hi);
                o0[rr] *= ar; o1[rr] *= ar;
            }
        }

        const float mb = mrun * LOG2E;
        #pragma unroll
        for (int rr = 0; rr < 16; ++rr) {
            sa[rr] = exp2f(fmaf(sa[rr], LOG2E, -mb));
            sb[rr] = exp2f(fmaf(sb[rr], LOG2E, -mb));
        }
        // row sum: depth-5 tree (was 32-deep serial chain)
        float tu[16];
        #pragma unroll
        for (int rr = 0; rr < 16; ++rr) tu[rr] = sa[rr] + sb[rr];
        #pragma unroll
        for (int s = 8; s > 0; s >>= 1)
            #pragma unroll
            for (int rr = 0; rr < s; ++rr) tu[rr] += tu[rr + s];
        lrun += tu[0] + __shfl_xor(tu[0], 32);

        // P -> PV A-fragments (T12)
        unsigned paw[4][4];
        #pragma unroll
        for (int ks = 0; ks < 4; ++ks) {
            const int e = 2 * ks, f = 2 * ks + 1;
            const int ra = 4 * (e & 3), rb = 4 * (f & 3);
            unsigned A0, A1, B0, B1;
            if (e >> 2) { A0 = pk_bf16(sb[ra], sb[ra + 1]); A1 = pk_bf16(sb[ra + 2], sb[ra + 3]); }
            else        { A0 = pk_bf16(sa[ra], sa[ra + 1]); A1 = pk_bf16(sa[ra + 2], sa[ra + 3]); }
            if (f >> 2) { B0 = pk_bf16(sb[rb], sb[rb + 1]); B1 = pk_bf16(sb[rb + 2], sb[rb + 3]); }
            else        { B0 = pk_bf16(sa[rb], sa[rb + 1]); B1 = pk_bf16(sa[rb + 2], sa[rb + 3]); }
            pl32_swap(A0, B0);
            pl32_swap(A1, B1);
            paw[ks][0] = A0; paw[ks][1] = A1; paw[ks][2] = B0; paw[ks][3] = B1;
        }

        // O += P * V from LDS V^T tile (swizzled reads)
        #pragma unroll
        for (int ks = 0; ks < 4; ++ks) {
            union { unsigned w[4]; bf16x8 v; } u;
            u.w[0] = paw[ks][0]; u.w[1] = paw[ks][1];
            u.w[2] = paw[ks][2]; u.w[3] = paw[ks][3];
            const bf16x8 v0 = *(const bf16x8*)&lV[p][ql]     [((2 * ks + hi) ^ qkey) * 8];
            const bf16x8 v1 = *(const bf16x8*)&lV[p][32 + ql][((2 * ks + hi) ^ qkey) * 8];
            o0 = MFMA32(u.v, v0, o0);
            o1 = MFMA32(u.v, v1, o1);
        }
    }

    // epilogue
    const float linv = 1.0f / fmaxf(lrun, 1e-30f);
    #pragma unroll
    for (int rr = 0; rr < 16; ++rr) {
        const int cr = (rr & 3) + 8 * (rr >> 2) + 4 * hi;
        const float li = __shfl(linv, cr);
        const int row = wrow0 + cr;
        O[(size_t)row * 64 + ql]      = f2bf(o0[rr] * li);
        O[(size_t)row * 64 + 32 + ql] = f2bf(o1[rr] * li);
    }
}

extern "C" void kernel_launch(void* const* d_in, const int* in_sizes, int n_in,
                              void* d_out, int out_size, void* d_ws, size_t ws_size,
                              hipStream_t stream) {
    const float* x  = (const float*)d_in[0];   // x_q  [4,2048,512] fp32
    const float* Wq = (const float*)d_in[1];   // [8,64,512] fp32
    const float* Wk = (const float*)d_in[2];
    const float* Wv = (const float*)d_in[3];
    const float* Wp = (const float*)d_in[4];   // [512,512] fp32
    const float* bp = (const float*)d_in[5];   // [512] fp32
    float* out = (float*)d_out;                // [4,2048,512] fp32

    const size_t NEL  = 4u * 8u * 2048u * 64u;   // 4,194,304 (all batches)
    const size_t NELB = 8u * 2048u * 64u;        // 1,048,576 (one batch)
    const float qscale = 0.04419417382415922f;   // 512^-0.5 folded into q

    if (ws_size >= 3u * NEL * sizeof(ushort)) {
        // d_out bytes: [xbf (bf16 x)][qb (bf16 q)] — final GEMM overwrites.
        // wbf (QKV bf16 weights) parks at ab; consumed by gemm_qkv3 BEFORE
        // attn overwrites ab. Wp stays fp32 (no safe parking past attn).
        ushort* xbf = (ushort*)d_out;
        ushort* qb  = xbf + NEL;
        ushort* kb  = (ushort*)d_ws;
        ushort* vb  = kb + NEL;                  // holds VT [b,h,d,2048]
        ushort* ab  = vb + NEL;
        ushort* wbf = ab;                        // 3*262144 ushorts = 1.5 MB
        hipLaunchKernelGGL(cvt_bf16, dim3((int)(NEL / (256 * 8))), dim3(256), 0, stream,
                           x, xbf, (int)NEL);
        hipLaunchKernelGGL(cvt_w3, dim3(384), dim3(256), 0, stream, Wq, Wk, Wv, wbf);
        hipLaunchKernelGGL(gemm_qkv3, dim3(64, 12), dim3(256), 0, stream,
                           xbf, wbf, qscale, qb, kb, vb);
        hipLaunchKernelGGL(attn_kernel, dim3(16, 32), dim3(256), 0, stream, qb, kb, vb, ab);
        hipLaunchKernelGGL(gemm_out, dim3(64, 4), dim3(256), 0, stream, ab, Wp, bp, out);
    } else {
        // per-batch fallback: ws need = 3 * NELB * 2 = 6.3 MB
        ushort* kb = (ushort*)d_ws;
        ushort* vb = kb + NELB;
        ushort* ab = vb + NELB;
        ushort* wbf = ab;                        // 1.5 MB slice
        for (int b = 0; b < 4; ++b) {
            const float* xb = x + (size_t)b * 2048u * 512u;
            float* ob = out + (size_t)b * 2048u * 512u;
            ushort* xbf = (ushort*)ob;           // batch slice: [xbf][qb]
            ushort* qb  = xbf + NELB;
            hipLaunchKernelGGL(cvt_bf16, dim3((int)(NELB / (256 * 8))), dim3(256), 0, stream,
                               xb, xbf, (int)NELB);
            hipLaunchKernelGGL(cvt_w3, dim3(384), dim3(256), 0, stream, Wq, Wk, Wv, wbf);
            hipLaunchKernelGGL(gemm_qkv3, dim3(16, 12), dim3(256), 0, stream,
                               xbf, wbf, qscale, qb, kb, vb);
            hipLaunchKernelGGL(attn_kernel, dim3(16, 8), dim3(256), 0, stream, qb, kb, vb, ab);
            hipLaunchKernelGGL(gemm_out, dim3(16, 4), dim3(256), 0, stream, ab, Wp, bp, ob);
        }
    }
}

// Round 14
// 99.200 us; speedup vs baseline: 1.3948x; 1.0495x over previous
//
#include <hip/hip_runtime.h>
#include <hip/hip_bf16.h>

using bf16x8 = __attribute__((ext_vector_type(8))) __bf16;
using f32x4  = __attribute__((ext_vector_type(4))) float;
using f32x16 = __attribute__((ext_vector_type(16))) float;
using i32x4  = __attribute__((ext_vector_type(4))) int;

#define MFMA_16x16x32(a, b, c) __builtin_amdgcn_mfma_f32_16x16x32_bf16((a), (b), (c), 0, 0, 0)
#define MFMA32(a, b, c)        __builtin_amdgcn_mfma_f32_32x32x16_bf16((a), (b), (c), 0, 0, 0)

// async global->LDS, 16 B per lane; LDS dest = wave-uniform base + lane*16
#define GLOAD16(g, l)                                                         \
    __builtin_amdgcn_global_load_lds(                                         \
        (const __attribute__((address_space(1))) unsigned int*)(g),           \
        (__attribute__((address_space(3))) unsigned int*)(l), 16, 0, 0)

__device__ __forceinline__ ushort f2bf(float f) {
    return __builtin_bit_cast(ushort, (__bf16)f);
}
__device__ __forceinline__ unsigned pk_bf16(float lo, float hi) {
    unsigned r;
    asm volatile("v_cvt_pk_bf16_f32 %0, %1, %2" : "=v"(r) : "v"(lo), "v"(hi));
    return r;
}
__device__ __forceinline__ void pl32_swap(unsigned &a, unsigned &b) {
    asm volatile("v_permlane32_swap_b32 %0, %1" : "+v"(a), "+v"(b));
}

// ---------------------------------------------------------------------------
// fp32 -> bf16 vectorized convert (8 elems/thread)
// ---------------------------------------------------------------------------
__global__ __launch_bounds__(256) void cvt_bf16(
    const float* __restrict__ in, ushort* __restrict__ out, int n)
{
    const int i = (blockIdx.x * 256 + threadIdx.x) * 8;
    if (i + 8 <= n) {
        const f32x4 a = *(const f32x4*)(in + i);
        const f32x4 b = *(const f32x4*)(in + i + 4);
        union { ushort u[8]; i32x4 w; } p;
        #pragma unroll
        for (int j = 0; j < 4; ++j) { p.u[j] = f2bf(a[j]); p.u[4 + j] = f2bf(b[j]); }
        *(i32x4*)(out + i) = p.w;
    }
}

// ---------------------------------------------------------------------------
// 3x QKV weights fp32 -> bf16, concat into wbf[3][512*512]
// ---------------------------------------------------------------------------
__global__ __launch_bounds__(256) void cvt_w3(
    const float* __restrict__ w0, const float* __restrict__ w1,
    const float* __restrict__ w2, ushort* __restrict__ out)
{
    const int i = (blockIdx.x * 256 + threadIdx.x) * 8;   // < 3*262144
    const int w = i >> 18, off = i & 262143;
    const float* src = (w == 0) ? w0 : ((w == 1) ? w1 : w2);
    const f32x4 a = *(const f32x4*)(src + off);
    const f32x4 b = *(const f32x4*)(src + off + 4);
    union { ushort u[8]; i32x4 v; } p;
    #pragma unroll
    for (int j = 0; j < 4; ++j) { p.u[j] = f2bf(a[j]); p.u[4 + j] = f2bf(b[j]); }
    *(i32x4*)(out + i) = p.v;
}

// ---------------------------------------------------------------------------
// Fused QKV GEMM, global_load_lds staging (R13-proven).
// blockIdx.y: (y>>2) selects {Wq,Wk,Wv}; (y&3) is the 128-col n-tile.
// q,k -> bf16 head-interleaved [b,h,t,64]; v -> TRANSPOSED [b,h,d,2048]
// ---------------------------------------------------------------------------
__global__ __launch_bounds__(256) void gemm_qkv3(
    const ushort* __restrict__ A, const ushort* __restrict__ Wbf,
    float qscale, ushort* __restrict__ qb, ushort* __restrict__ kb,
    ushort* __restrict__ vb)
{
    __shared__ ushort lA[2][128][32];
    __shared__ ushort lB[2][128][32];
    const int wsel = blockIdx.y >> 2;
    const int n0 = (blockIdx.y & 3) * 128;
    const ushort* W = Wbf + wsel * 262144;
    ushort* out = (wsel == 0) ? qb : ((wsel == 1) ? kb : vb);
    const float scale = (wsel == 0) ? qscale : 1.0f;

    const int m0 = blockIdx.x * 128;
    const int tid  = threadIdx.x;
    const int lane = tid & 63;
    const int wave = tid >> 6;
    const int wr = (wave >> 1) * 64, wc = (wave & 1) * 64;
    const int frow = lane & 15;
    const int fkp  = (((lane >> 4) ^ ((lane >> 1) & 3))) * 8;

    const int srw  = lane >> 2;
    const int scol = ((lane & 3) ^ ((lane >> 3) & 3)) * 8;

    f32x4 acc[4][4] = {};
    auto stage = [&](int k0, int b) {
        #pragma unroll
        for (int i = 0; i < 2; ++i) {
            const int rb = (wave * 2 + i) * 16;
            GLOAD16(A + (size_t)(m0 + rb + srw) * 512 + k0 + scol, &lA[b][rb][0]);
            GLOAD16(W + (size_t)(n0 + rb + srw) * 512 + k0 + scol, &lB[b][rb][0]);
        }
    };

    stage(0, 0);
    for (int t = 0; t < 16; ++t) {
        const int p = t & 1;
        __syncthreads();
        if (t + 1 < 16) stage((t + 1) * 32, p ^ 1);

        bf16x8 af[4], bg[4];
        #pragma unroll
        for (int m = 0; m < 4; ++m) af[m] = *(const bf16x8*)&lA[p][wr + m * 16 + frow][fkp];
        #pragma unroll
        for (int n = 0; n < 4; ++n) bg[n] = *(const bf16x8*)&lB[p][wc + n * 16 + frow][fkp];
        #pragma unroll
        for (int m = 0; m < 4; ++m)
            #pragma unroll
            for (int n = 0; n < 4; ++n)
                acc[m][n] = MFMA_16x16x32(af[m], bg[n], acc[m][n]);
    }

    const int rbase = (lane >> 4) * 4;
    const int ccol  = lane & 15;
    if (wsel == 2) {
        #pragma unroll
        for (int m = 0; m < 4; ++m)
            #pragma unroll
            for (int n = 0; n < 4; ++n) {
                const int col = n0 + wc + n * 16 + ccol;
                const int row0 = m0 + wr + m * 16 + rbase;
                unsigned long long u = 0;
                #pragma unroll
                for (int r = 0; r < 4; ++r)
                    u |= ((unsigned long long)f2bf(acc[m][n][r])) << (16 * r);
                const size_t idx = ((size_t)((row0 >> 11) * 8 + (col >> 6)) * 64
                                    + (col & 63)) * 2048 + (row0 & 2047);
                *(unsigned long long*)(out + idx) = u;
            }
    } else {
        #pragma unroll
        for (int m = 0; m < 4; ++m)
            #pragma unroll
            for (int n = 0; n < 4; ++n) {
                const int col = n0 + wc + n * 16 + ccol;
                #pragma unroll
                for (int r = 0; r < 4; ++r) {
                    const int row = m0 + wr + m * 16 + rbase + r;
                    out[(((row >> 11) * 8 + (col >> 6)) * 2048 + (row & 2047)) * 64 + (col & 63)]
                        = f2bf(acc[m][n][r] * scale);
                }
            }
    }
}

// ---------------------------------------------------------------------------
// Output GEMM, glds staging + bf16 Wp: C[M,512](fp32) = A(bf16,head-il)*W^T+bp
// ---------------------------------------------------------------------------
__global__ __launch_bounds__(256) void gemm_out(
    const ushort* __restrict__ A, const ushort* __restrict__ W,
    const float* __restrict__ bias, float* __restrict__ out)
{
    __shared__ ushort lA[2][128][32];
    __shared__ ushort lB[2][128][32];
    const int m0 = blockIdx.x * 128;
    const int n0 = blockIdx.y * 128;
    const int tid  = threadIdx.x;
    const int lane = tid & 63;
    const int wave = tid >> 6;
    const int wr = (wave >> 1) * 64, wc = (wave & 1) * 64;
    const int frow = lane & 15;
    const int fkp  = (((lane >> 4) ^ ((lane >> 1) & 3))) * 8;

    const int srw  = lane >> 2;
    const int scol = ((lane & 3) ^ ((lane >> 3) & 3)) * 8;

    f32x4 acc[4][4] = {};
    auto stage = [&](int k0, int b) {
        #pragma unroll
        for (int i = 0; i < 2; ++i) {
            const int rb = (wave * 2 + i) * 16;
            const int row = m0 + rb + srw, c = k0 + scol;
            const size_t ia = (((size_t)(row >> 11) * 8 + (c >> 6)) * 2048
                               + (row & 2047)) * 64 + (c & 63);
            GLOAD16(A + ia, &lA[b][rb][0]);
            GLOAD16(W + (size_t)(n0 + rb + srw) * 512 + k0 + scol, &lB[b][rb][0]);
        }
    };

    stage(0, 0);
    for (int t = 0; t < 16; ++t) {
        const int p = t & 1;
        __syncthreads();
        if (t + 1 < 16) stage((t + 1) * 32, p ^ 1);

        bf16x8 af[4], bg[4];
        #pragma unroll
        for (int m = 0; m < 4; ++m) af[m] = *(const bf16x8*)&lA[p][wr + m * 16 + frow][fkp];
        #pragma unroll
        for (int n = 0; n < 4; ++n) bg[n] = *(const bf16x8*)&lB[p][wc + n * 16 + frow][fkp];
        #pragma unroll
        for (int m = 0; m < 4; ++m)
            #pragma unroll
            for (int n = 0; n < 4; ++n)
                acc[m][n] = MFMA_16x16x32(af[m], bg[n], acc[m][n]);
    }

    const int rbase = (lane >> 4) * 4;
    const int ccol  = lane & 15;
    #pragma unroll
    for (int m = 0; m < 4; ++m)
        #pragma unroll
        for (int n = 0; n < 4; ++n) {
            const int col = n0 + wc + n * 16 + ccol;
            const float bv = bias[col];
            #pragma unroll
            for (int r = 0; r < 4; ++r) {
                const int row = m0 + wr + m * 16 + rbase + r;
                out[row * 512 + col] = acc[m][n][r] + bv;
            }
        }
}

// ---------------------------------------------------------------------------
// Causal flash attention R14: KVBLK=128 (two 64-col sub-tiles per barrier
// period -> half the barriers, double the compute per period). 4 waves x 128
// q-rows, K/V LDS double-buffer (XOR-swizzled), per-wave swapped-QK^T 32x32
// in-register softmax (R7 math unchanged). q,k: [bh][t][64]; vt: [bh][d][2048].
// ---------------------------------------------------------------------------
__global__ __launch_bounds__(256, 2) void attn_kernel(
    const ushort* __restrict__ q, const ushort* __restrict__ k,
    const ushort* __restrict__ vt, ushort* __restrict__ att)
{
    __shared__ ushort lK[2][2][64][64];   // [buf][half][s_local][d]
    __shared__ ushort lV[2][2][64][64];   // [buf][half][d][s_local]

    const int NB   = (int)(gridDim.x * gridDim.y);
    const int NH   = NB >> 4;
    const int half = NB >> 1;
    const int n    = (int)(blockIdx.y * gridDim.x + blockIdx.x);
    const int r    = (n < half) ? n : (NB - 1 - (n - half));
    const int qt0  = (15 - r / NH) * 128;    // heavy-first
    const int bh   = r % NH;

    const ushort* Q  = q  + (size_t)bh * 2048 * 64;
    const ushort* K  = k  + (size_t)bh * 2048 * 64;
    const ushort* VT = vt + (size_t)bh * 2048 * 64;
    ushort* O = att + (size_t)bh * 2048 * 64;

    const int tid = threadIdx.x;
    const int wv  = tid >> 6;
    const int l   = tid & 63;
    const int ql  = l & 31;
    const int hi  = l >> 5;
    const int wrow0 = qt0 + wv * 32;
    const int qrow  = wrow0 + ql;
    const int wmax  = wrow0 + 31;
    const int qkey  = ql & 7;
    const float LOG2E = 1.44269504088896f;

    const int srow = tid >> 2;
    const int sg   = (tid & 3) * 2;
    const int skey = srow & 7;

    bf16x8 aq[4];
    #pragma unroll
    for (int kk = 0; kk < 4; ++kk)
        aq[kk] = *(const bf16x8*)(Q + (size_t)qrow * 64 + kk * 16 + hi * 8);

    f32x16 o0 = {}, o1 = {};
    float mrun = -30000.0f, lrun = 0.0f;
    const int nt2 = qt0 / 128 + 1;        // 128-wide KV tiles

    i32x4 kr[2][2], vr[2][2];             // [half][pair]
    auto loadG = [&](int s0) {
        #pragma unroll
        for (int hf = 0; hf < 2; ++hf) {
            const ushort* kp = K + (size_t)(s0 + hf * 64 + srow) * 64 + (tid & 3) * 16;
            kr[hf][0] = *(const i32x4*)(kp);
            kr[hf][1] = *(const i32x4*)(kp + 8);
            const ushort* vp = VT + (size_t)srow * 2048 + s0 + hf * 64 + (tid & 3) * 16;
            vr[hf][0] = *(const i32x4*)(vp);
            vr[hf][1] = *(const i32x4*)(vp + 8);
        }
    };
    auto writeL = [&](int b) {
        #pragma unroll
        for (int hf = 0; hf < 2; ++hf) {
            *(i32x4*)&lK[b][hf][srow][((sg    ) ^ skey) * 8] = kr[hf][0];
            *(i32x4*)&lK[b][hf][srow][((sg + 1) ^ skey) * 8] = kr[hf][1];
            *(i32x4*)&lV[b][hf][srow][((sg    ) ^ skey) * 8] = vr[hf][0];
            *(i32x4*)&lV[b][hf][srow][((sg + 1) ^ skey) * 8] = vr[hf][1];
        }
    };

    loadG(0);
    writeL(0);
    if (nt2 > 1) loadG(128);

    for (int T = 0; T < nt2; ++T) {
        const int p  = T & 1;
        const int s0 = T * 128;
        __syncthreads();
        if (T + 1 < nt2) writeL(p ^ 1);
        if (T + 2 < nt2) loadG(s0 + 256);

        #pragma unroll
        for (int hf = 0; hf < 2; ++hf) {
            const int ss = s0 + hf * 64;
            if (ss > wmax) continue;      // fully-masked sub-tile

            // S^T = K * Q^T from LDS (swizzled reads)
            f32x16 sa = {}, sb = {};
            #pragma unroll
            for (int kk = 0; kk < 4; ++kk) {
                const bf16x8 kb0 = *(const bf16x8*)&lK[p][hf][ql]     [((2 * kk + hi) ^ qkey) * 8];
                const bf16x8 kb1 = *(const bf16x8*)&lK[p][hf][32 + ql][((2 * kk + hi) ^ qkey) * 8];
                sa = MFMA32(kb0, aq[kk], sa);
                sb = MFMA32(kb1, aq[kk], sb);
            }

            if (ss + 63 > wrow0) {
                #pragma unroll
                for (int rr = 0; rr < 16; ++rr) {
                    const int cr = (rr & 3) + 8 * (rr >> 2) + 4 * hi;
                    if (ss + cr > qrow)      sa[rr] = -30000.0f;
                    if (ss + 32 + cr > qrow) sb[rr] = -30000.0f;
                }
            }

            // row max: depth-5 tree
            float tm[16];
            #pragma unroll
            for (int rr = 0; rr < 16; ++rr) tm[rr] = fmaxf(sa[rr], sb[rr]);
            #pragma unroll
            for (int s = 8; s > 0; s >>= 1)
                #pragma unroll
                for (int rr = 0; rr < s; ++rr) tm[rr] = fmaxf(tm[rr], tm[rr + s]);
            float pmax = fmaxf(tm[0], __shfl_xor(tm[0], 32));

            // defer-max (T13)
            if (__any(pmax > mrun + 8.0f)) {
                const float mnew  = fmaxf(mrun, pmax);
                const float alpha = exp2f((mrun - mnew) * LOG2E);
                mrun = mnew;
                lrun *= alpha;
                #pragma unroll
                for (int rr = 0; rr < 16; ++rr) {
                    const float ar = __shfl(alpha, (rr & 3) + 8 * (rr >> 2) + 4 * hi);
                    o0[rr] *= ar; o1[rr] *= ar;
                }
            }

            const float mb = mrun * LOG2E;
            #pragma unroll
            for (int rr = 0; rr < 16; ++rr) {
                sa[rr] = exp2f(fmaf(sa[rr], LOG2E, -mb));
                sb[rr] = exp2f(fmaf(sb[rr], LOG2E, -mb));
            }
            float tu[16];
            #pragma unroll
            for (int rr = 0; rr < 16; ++rr) tu[rr] = sa[rr] + sb[rr];
            #pragma unroll
            for (int s = 8; s > 0; s >>= 1)
                #pragma unroll
                for (int rr = 0; rr < s; ++rr) tu[rr] += tu[rr + s];
            lrun += tu[0] + __shfl_xor(tu[0], 32);

            // P -> PV A-fragments (T12)
            unsigned paw[4][4];
            #pragma unroll
            for (int ks = 0; ks < 4; ++ks) {
                const int e = 2 * ks, f = 2 * ks + 1;
                const int ra = 4 * (e & 3), rb = 4 * (f & 3);
                unsigned A0, A1, B0, B1;
                if (e >> 2) { A0 = pk_bf16(sb[ra], sb[ra + 1]); A1 = pk_bf16(sb[ra + 2], sb[ra + 3]); }
                else        { A0 = pk_bf16(sa[ra], sa[ra + 1]); A1 = pk_bf16(sa[ra + 2], sa[ra + 3]); }
                if (f >> 2) { B0 = pk_bf16(sb[rb], sb[rb + 1]); B1 = pk_bf16(sb[rb + 2], sb[rb + 3]); }
                else        { B0 = pk_bf16(sa[rb], sa[rb + 1]); B1 = pk_bf16(sa[rb + 2], sa[rb + 3]); }
                pl32_swap(A0, B0);
                pl32_swap(A1, B1);
                paw[ks][0] = A0; paw[ks][1] = A1; paw[ks][2] = B0; paw[ks][3] = B1;
            }

            // O += P * V from LDS V^T sub-tile (swizzled reads)
            #pragma unroll
            for (int ks = 0; ks < 4; ++ks) {
                union { unsigned w[4]; bf16x8 v; } u;
                u.w[0] = paw[ks][0]; u.w[1] = paw[ks][1];
                u.w[2] = paw[ks][2]; u.w[3] = paw[ks][3];
                const bf16x8 v0 = *(const bf16x8*)&lV[p][hf][ql]     [((2 * ks + hi) ^ qkey) * 8];
                const bf16x8 v1 = *(const bf16x8*)&lV[p][hf][32 + ql][((2 * ks + hi) ^ qkey) * 8];
                o0 = MFMA32(u.v, v0, o0);
                o1 = MFMA32(u.v, v1, o1);
            }
        }
    }

    // epilogue
    const float linv = 1.0f / fmaxf(lrun, 1e-30f);
    #pragma unroll
    for (int rr = 0; rr < 16; ++rr) {
        const int cr = (rr & 3) + 8 * (rr >> 2) + 4 * hi;
        const float li = __shfl(linv, cr);
        const int row = wrow0 + cr;
        O[(size_t)row * 64 + ql]      = f2bf(o0[rr] * li);
        O[(size_t)row * 64 + 32 + ql] = f2bf(o1[rr] * li);
    }
}

extern "C" void kernel_launch(void* const* d_in, const int* in_sizes, int n_in,
                              void* d_out, int out_size, void* d_ws, size_t ws_size,
                              hipStream_t stream) {
    const float* x  = (const float*)d_in[0];   // x_q  [4,2048,512] fp32
    const float* Wq = (const float*)d_in[1];   // [8,64,512] fp32
    const float* Wk = (const float*)d_in[2];
    const float* Wv = (const float*)d_in[3];
    const float* Wp = (const float*)d_in[4];   // [512,512] fp32
    const float* bp = (const float*)d_in[5];   // [512] fp32
    float* out = (float*)d_out;                // [4,2048,512] fp32

    const size_t NEL  = 4u * 8u * 2048u * 64u;   // 4,194,304 (all batches)
    const size_t NELB = 8u * 2048u * 64u;        // 1,048,576 (one batch)
    const float qscale = 0.04419417382415922f;   // 512^-0.5 folded into q

    if (ws_size >= 3u * NEL * sizeof(ushort)) {
        // d_out bytes: [xbf][qb]; final GEMM overwrites d_out.
        // wbf (QKV bf16) parks at ab (consumed by gemm_qkv3 before attn).
        // wpbf (Wp bf16) parks at kb AFTER attn (kb's last consumer is attn;
        // gemm_out reads ab+wpbf and writes d_out only -> no overlap).
        ushort* xbf  = (ushort*)d_out;
        ushort* qb   = xbf + NEL;
        ushort* kb   = (ushort*)d_ws;
        ushort* vb   = kb + NEL;                 // holds VT [b,h,d,2048]
        ushort* ab   = vb + NEL;
        ushort* wbf  = ab;                       // 1.5 MB
        ushort* wpbf = kb;                       // 0.5 MB, valid post-attn
        hipLaunchKernelGGL(cvt_bf16, dim3((int)(NEL / (256 * 8))), dim3(256), 0, stream,
                           x, xbf, (int)NEL);
        hipLaunchKernelGGL(cvt_w3, dim3(384), dim3(256), 0, stream, Wq, Wk, Wv, wbf);
        hipLaunchKernelGGL(gemm_qkv3, dim3(64, 12), dim3(256), 0, stream,
                           xbf, wbf, qscale, qb, kb, vb);
        hipLaunchKernelGGL(attn_kernel, dim3(16, 32), dim3(256), 0, stream, qb, kb, vb, ab);
        hipLaunchKernelGGL(cvt_bf16, dim3(128), dim3(256), 0, stream, Wp, wpbf, 262144);
        hipLaunchKernelGGL(gemm_out, dim3(64, 4), dim3(256), 0, stream, ab, wpbf, bp, out);
    } else {
        // per-batch fallback: ws need = 3 * NELB * 2 = 6.3 MB
        ushort* kb  = (ushort*)d_ws;
        ushort* vb  = kb + NELB;
        ushort* ab  = vb + NELB;
        ushort* wbf = ab;                        // 1.5 MB slice
        for (int b = 0; b < 4; ++b) {
            const float* xb = x + (size_t)b * 2048u * 512u;
            float* ob = out + (size_t)b * 2048u * 512u;
            ushort* xbf  = (ushort*)ob;          // batch slice: [xbf][qb]
            ushort* qb   = xbf + NELB;
            ushort* wpbf = kb;                   // valid post-attn (batch b)
            hipLaunchKernelGGL(cvt_bf16, dim3((int)(NELB / (256 * 8))), dim3(256), 0, stream,
                               xb, xbf, (int)NELB);
            hipLaunchKernelGGL(cvt_w3, dim3(384), dim3(256), 0, stream, Wq, Wk, Wv, wbf);
            hipLaunchKernelGGL(gemm_qkv3, dim3(16, 12), dim3(256), 0, stream,
                               xbf, wbf, qscale, qb, kb, vb);
            hipLaunchKernelGGL(attn_kernel, dim3(16, 8), dim3(256), 0, stream, qb, kb, vb, ab);
            hipLaunchKernelGGL(cvt_bf16, dim3(128), dim3(256), 0, stream, Wp, wpbf, 262144);
            hipLaunchKernelGGL(gemm_out, dim3(16, 4), dim3(256), 0, stream, ab, wpbf, bp, ob);
        }
    }
}

// Round 15
// 94.206 us; speedup vs baseline: 1.4687x; 1.0530x over previous
//
#include <hip/hip_runtime.h>
#include <hip/hip_bf16.h>

using bf16x8 = __attribute__((ext_vector_type(8))) __bf16;
using f32x4  = __attribute__((ext_vector_type(4))) float;
using f32x16 = __attribute__((ext_vector_type(16))) float;
using i32x4  = __attribute__((ext_vector_type(4))) int;

#define MFMA_16x16x32(a, b, c) __builtin_amdgcn_mfma_f32_16x16x32_bf16((a), (b), (c), 0, 0, 0)
#define MFMA32(a, b, c)        __builtin_amdgcn_mfma_f32_32x32x16_bf16((a), (b), (c), 0, 0, 0)

// async global->LDS, 16 B per lane; LDS dest = wave-uniform base + lane*16
#define GLOAD16(g, l)                                                         \
    __builtin_amdgcn_global_load_lds(                                         \
        (const __attribute__((address_space(1))) unsigned int*)(g),           \
        (__attribute__((address_space(3))) unsigned int*)(l), 16, 0, 0)

__device__ __forceinline__ ushort f2bf(float f) {
    return __builtin_bit_cast(ushort, (__bf16)f);
}
__device__ __forceinline__ unsigned pk_bf16(float lo, float hi) {
    unsigned r;
    asm volatile("v_cvt_pk_bf16_f32 %0, %1, %2" : "=v"(r) : "v"(lo), "v"(hi));
    return r;
}
__device__ __forceinline__ void pl32_swap(unsigned &a, unsigned &b) {
    asm volatile("v_permlane32_swap_b32 %0, %1" : "+v"(a), "+v"(b));
}

// ---------------------------------------------------------------------------
// fp32 -> bf16 vectorized convert (8 elems/thread)
// ---------------------------------------------------------------------------
__global__ __launch_bounds__(256) void cvt_bf16(
    const float* __restrict__ in, ushort* __restrict__ out, int n)
{
    const int i = (blockIdx.x * 256 + threadIdx.x) * 8;
    if (i + 8 <= n) {
        const f32x4 a = *(const f32x4*)(in + i);
        const f32x4 b = *(const f32x4*)(in + i + 4);
        union { ushort u[8]; i32x4 w; } p;
        #pragma unroll
        for (int j = 0; j < 4; ++j) { p.u[j] = f2bf(a[j]); p.u[4 + j] = f2bf(b[j]); }
        *(i32x4*)(out + i) = p.w;
    }
}

// ---------------------------------------------------------------------------
// Fused convert: blocks [0,nxb) convert x (nx elems); blocks [nxb, nxb+384)
// convert Wq/Wk/Wv into wbf[3][512*512].
// ---------------------------------------------------------------------------
__global__ __launch_bounds__(256) void cvt_fused(
    const float* __restrict__ x, ushort* __restrict__ xbf, int nx, int nxb,
    const float* __restrict__ w0, const float* __restrict__ w1,
    const float* __restrict__ w2, ushort* __restrict__ wbf)
{
    const int b = (int)blockIdx.x;
    if (b < nxb) {
        const int i = (b * 256 + (int)threadIdx.x) * 8;
        if (i + 8 <= nx) {
            const f32x4 a = *(const f32x4*)(x + i);
            const f32x4 c = *(const f32x4*)(x + i + 4);
            union { ushort u[8]; i32x4 w; } p;
            #pragma unroll
            for (int j = 0; j < 4; ++j) { p.u[j] = f2bf(a[j]); p.u[4 + j] = f2bf(c[j]); }
            *(i32x4*)(xbf + i) = p.w;
        }
    } else {
        const int i = ((b - nxb) * 256 + (int)threadIdx.x) * 8;   // < 3*262144
        const int w = i >> 18, off = i & 262143;
        const float* src = (w == 0) ? w0 : ((w == 1) ? w1 : w2);
        const f32x4 a = *(const f32x4*)(src + off);
        const f32x4 c = *(const f32x4*)(src + off + 4);
        union { ushort u[8]; i32x4 v; } p;
        #pragma unroll
        for (int j = 0; j < 4; ++j) { p.u[j] = f2bf(a[j]); p.u[4 + j] = f2bf(c[j]); }
        *(i32x4*)(wbf + i) = p.v;
    }
}

// ---------------------------------------------------------------------------
// Fused QKV GEMM, global_load_lds staging (R13-proven).
// ---------------------------------------------------------------------------
__global__ __launch_bounds__(256) void gemm_qkv3(
    const ushort* __restrict__ A, const ushort* __restrict__ Wbf,
    float qscale, ushort* __restrict__ qb, ushort* __restrict__ kb,
    ushort* __restrict__ vb)
{
    __shared__ ushort lA[2][128][32];
    __shared__ ushort lB[2][128][32];
    const int wsel = blockIdx.y >> 2;
    const int n0 = (blockIdx.y & 3) * 128;
    const ushort* W = Wbf + wsel * 262144;
    ushort* out = (wsel == 0) ? qb : ((wsel == 1) ? kb : vb);
    const float scale = (wsel == 0) ? qscale : 1.0f;

    const int m0 = blockIdx.x * 128;
    const int tid  = threadIdx.x;
    const int lane = tid & 63;
    const int wave = tid >> 6;
    const int wr = (wave >> 1) * 64, wc = (wave & 1) * 64;
    const int frow = lane & 15;
    const int fkp  = (((lane >> 4) ^ ((lane >> 1) & 3))) * 8;

    const int srw  = lane >> 2;
    const int scol = ((lane & 3) ^ ((lane >> 3) & 3)) * 8;

    f32x4 acc[4][4] = {};
    auto stage = [&](int k0, int b) {
        #pragma unroll
        for (int i = 0; i < 2; ++i) {
            const int rb = (wave * 2 + i) * 16;
            GLOAD16(A + (size_t)(m0 + rb + srw) * 512 + k0 + scol, &lA[b][rb][0]);
            GLOAD16(W + (size_t)(n0 + rb + srw) * 512 + k0 + scol, &lB[b][rb][0]);
        }
    };

    stage(0, 0);
    for (int t = 0; t < 16; ++t) {
        const int p = t & 1;
        __syncthreads();
        if (t + 1 < 16) stage((t + 1) * 32, p ^ 1);

        bf16x8 af[4], bg[4];
        #pragma unroll
        for (int m = 0; m < 4; ++m) af[m] = *(const bf16x8*)&lA[p][wr + m * 16 + frow][fkp];
        #pragma unroll
        for (int n = 0; n < 4; ++n) bg[n] = *(const bf16x8*)&lB[p][wc + n * 16 + frow][fkp];
        #pragma unroll
        for (int m = 0; m < 4; ++m)
            #pragma unroll
            for (int n = 0; n < 4; ++n)
                acc[m][n] = MFMA_16x16x32(af[m], bg[n], acc[m][n]);
    }

    const int rbase = (lane >> 4) * 4;
    const int ccol  = lane & 15;
    if (wsel == 2) {
        #pragma unroll
        for (int m = 0; m < 4; ++m)
            #pragma unroll
            for (int n = 0; n < 4; ++n) {
                const int col = n0 + wc + n * 16 + ccol;
                const int row0 = m0 + wr + m * 16 + rbase;
                unsigned long long u = 0;
                #pragma unroll
                for (int r = 0; r < 4; ++r)
                    u |= ((unsigned long long)f2bf(acc[m][n][r])) << (16 * r);
                const size_t idx = ((size_t)((row0 >> 11) * 8 + (col >> 6)) * 64
                                    + (col & 63)) * 2048 + (row0 & 2047);
                *(unsigned long long*)(out + idx) = u;
            }
    } else {
        #pragma unroll
        for (int m = 0; m < 4; ++m)
            #pragma unroll
            for (int n = 0; n < 4; ++n) {
                const int col = n0 + wc + n * 16 + ccol;
                #pragma unroll
                for (int r = 0; r < 4; ++r) {
                    const int row = m0 + wr + m * 16 + rbase + r;
                    out[(((row >> 11) * 8 + (col >> 6)) * 2048 + (row & 2047)) * 64 + (col & 63)]
                        = f2bf(acc[m][n][r] * scale);
                }
            }
    }
}

// ---------------------------------------------------------------------------
// Output GEMM, glds staging + bf16 Wp (R14-proven).
// ---------------------------------------------------------------------------
__global__ __launch_bounds__(256) void gemm_out(
    const ushort* __restrict__ A, const ushort* __restrict__ W,
    const float* __restrict__ bias, float* __restrict__ out)
{
    __shared__ ushort lA[2][128][32];
    __shared__ ushort lB[2][128][32];
    const int m0 = blockIdx.x * 128;
    const int n0 = blockIdx.y * 128;
    const int tid  = threadIdx.x;
    const int lane = tid & 63;
    const int wave = tid >> 6;
    const int wr = (wave >> 1) * 64, wc = (wave & 1) * 64;
    const int frow = lane & 15;
    const int fkp  = (((lane >> 4) ^ ((lane >> 1) & 3))) * 8;

    const int srw  = lane >> 2;
    const int scol = ((lane & 3) ^ ((lane >> 3) & 3)) * 8;

    f32x4 acc[4][4] = {};
    auto stage = [&](int k0, int b) {
        #pragma unroll
        for (int i = 0; i < 2; ++i) {
            const int rb = (wave * 2 + i) * 16;
            const int row = m0 + rb + srw, c = k0 + scol;
            const size_t ia = (((size_t)(row >> 11) * 8 + (c >> 6)) * 2048
                               + (row & 2047)) * 64 + (c & 63);
            GLOAD16(A + ia, &lA[b][rb][0]);
            GLOAD16(W + (size_t)(n0 + rb + srw) * 512 + k0 + scol, &lB[b][rb][0]);
        }
    };

    stage(0, 0);
    for (int t = 0; t < 16; ++t) {
        const int p = t & 1;
        __syncthreads();
        if (t + 1 < 16) stage((t + 1) * 32, p ^ 1);

        bf16x8 af[4], bg[4];
        #pragma unroll
        for (int m = 0; m < 4; ++m) af[m] = *(const bf16x8*)&lA[p][wr + m * 16 + frow][fkp];
        #pragma unroll
        for (int n = 0; n < 4; ++n) bg[n] = *(const bf16x8*)&lB[p][wc + n * 16 + frow][fkp];
        #pragma unroll
        for (int m = 0; m < 4; ++m)
            #pragma unroll
            for (int n = 0; n < 4; ++n)
                acc[m][n] = MFMA_16x16x32(af[m], bg[n], acc[m][n]);
    }

    const int rbase = (lane >> 4) * 4;
    const int ccol  = lane & 15;
    #pragma unroll
    for (int m = 0; m < 4; ++m)
        #pragma unroll
        for (int n = 0; n < 4; ++n) {
            const int col = n0 + wc + n * 16 + ccol;
            const float bv = bias[col];
            #pragma unroll
            for (int r = 0; r < 4; ++r) {
                const int row = m0 + wr + m * 16 + rbase + r;
                out[row * 512 + col] = acc[m][n][r] + bv;
            }
        }
}

// ---------------------------------------------------------------------------
// Causal flash attention R15: KVBLK=128 with COMBINED 128-col softmax (one
// max-tree/rescale/sum per KV tile instead of two). 4 waves x 128 q-rows,
// K/V LDS double-buffer (XOR-swizzled), swapped-QK^T 32x32 in-reg softmax.
// ---------------------------------------------------------------------------
__global__ __launch_bounds__(256, 2) void attn_kernel(
    const ushort* __restrict__ q, const ushort* __restrict__ k,
    const ushort* __restrict__ vt, ushort* __restrict__ att)
{
    __shared__ ushort lK[2][2][64][64];   // [buf][half][s_local][d]
    __shared__ ushort lV[2][2][64][64];   // [buf][half][d][s_local]

    const int NB   = (int)(gridDim.x * gridDim.y);
    const int NH   = NB >> 4;
    const int half = NB >> 1;
    const int n    = (int)(blockIdx.y * gridDim.x + blockIdx.x);
    const int r    = (n < half) ? n : (NB - 1 - (n - half));
    const int qt0  = (15 - r / NH) * 128;    // heavy-first
    const int bh   = r % NH;

    const ushort* Q  = q  + (size_t)bh * 2048 * 64;
    const ushort* K  = k  + (size_t)bh * 2048 * 64;
    const ushort* VT = vt + (size_t)bh * 2048 * 64;
    ushort* O = att + (size_t)bh * 2048 * 64;

    const int tid = threadIdx.x;
    const int wv  = tid >> 6;
    const int l   = tid & 63;
    const int ql  = l & 31;
    const int hi  = l >> 5;
    const int wrow0 = qt0 + wv * 32;
    const int qrow  = wrow0 + ql;
    const int wmax  = wrow0 + 31;
    const int qkey  = ql & 7;
    const float LOG2E = 1.44269504088896f;

    const int srow = tid >> 2;
    const int sg   = (tid & 3) * 2;
    const int skey = srow & 7;

    bf16x8 aq[4];
    #pragma unroll
    for (int kk = 0; kk < 4; ++kk)
        aq[kk] = *(const bf16x8*)(Q + (size_t)qrow * 64 + kk * 16 + hi * 8);

    f32x16 o0 = {}, o1 = {};
    float mrun = -30000.0f, lrun = 0.0f;
    const int nt2 = qt0 / 128 + 1;

    i32x4 kr[2][2], vr[2][2];
    auto loadG = [&](int s0) {
        #pragma unroll
        for (int hf = 0; hf < 2; ++hf) {
            const ushort* kp = K + (size_t)(s0 + hf * 64 + srow) * 64 + (tid & 3) * 16;
            kr[hf][0] = *(const i32x4*)(kp);
            kr[hf][1] = *(const i32x4*)(kp + 8);
            const ushort* vp = VT + (size_t)srow * 2048 + s0 + hf * 64 + (tid & 3) * 16;
            vr[hf][0] = *(const i32x4*)(vp);
            vr[hf][1] = *(const i32x4*)(vp + 8);
        }
    };
    auto writeL = [&](int b) {
        #pragma unroll
        for (int hf = 0; hf < 2; ++hf) {
            *(i32x4*)&lK[b][hf][srow][((sg    ) ^ skey) * 8] = kr[hf][0];
            *(i32x4*)&lK[b][hf][srow][((sg + 1) ^ skey) * 8] = kr[hf][1];
            *(i32x4*)&lV[b][hf][srow][((sg    ) ^ skey) * 8] = vr[hf][0];
            *(i32x4*)&lV[b][hf][srow][((sg + 1) ^ skey) * 8] = vr[hf][1];
        }
    };

    loadG(0);
    writeL(0);
    if (nt2 > 1) loadG(128);

    for (int T = 0; T < nt2; ++T) {
        const int p  = T & 1;
        const int s0 = T * 128;
        __syncthreads();
        if (T + 1 < nt2) writeL(p ^ 1);
        if (T + 2 < nt2) loadG(s0 + 256);

        const bool act1 = (s0 + 64 <= wmax);   // hf1 sub-tile has unmasked rows
        // hf0 is always active: s0 <= qt0 <= wrow0 <= wmax

        // QK^T both halves (one long MFMA cluster)
        f32x16 sa0 = {}, sb0 = {}, sa1 = {}, sb1 = {};
        #pragma unroll
        for (int kk = 0; kk < 4; ++kk) {
            const bf16x8 a0 = *(const bf16x8*)&lK[p][0][ql]     [((2 * kk + hi) ^ qkey) * 8];
            const bf16x8 b0 = *(const bf16x8*)&lK[p][0][32 + ql][((2 * kk + hi) ^ qkey) * 8];
            sa0 = MFMA32(a0, aq[kk], sa0);
            sb0 = MFMA32(b0, aq[kk], sb0);
        }
        if (act1) {
            #pragma unroll
            for (int kk = 0; kk < 4; ++kk) {
                const bf16x8 a1 = *(const bf16x8*)&lK[p][1][ql]     [((2 * kk + hi) ^ qkey) * 8];
                const bf16x8 b1 = *(const bf16x8*)&lK[p][1][32 + ql][((2 * kk + hi) ^ qkey) * 8];
                sa1 = MFMA32(a1, aq[kk], sa1);
                sb1 = MFMA32(b1, aq[kk], sb1);
            }
        }

        // causal mask per half
        if (s0 + 63 > wrow0) {
            #pragma unroll
            for (int rr = 0; rr < 16; ++rr) {
                const int cr = (rr & 3) + 8 * (rr >> 2) + 4 * hi;
                if (s0 + cr > qrow)      sa0[rr] = -30000.0f;
                if (s0 + 32 + cr > qrow) sb0[rr] = -30000.0f;
            }
        }
        if (act1 && (s0 + 127 > wrow0)) {
            #pragma unroll
            for (int rr = 0; rr < 16; ++rr) {
                const int cr = (rr & 3) + 8 * (rr >> 2) + 4 * hi;
                if (s0 + 64 + cr > qrow) sa1[rr] = -30000.0f;
                if (s0 + 96 + cr > qrow) sb1[rr] = -30000.0f;
            }
        }

        // combined max tree over all active columns
        float tm[16];
        #pragma unroll
        for (int rr = 0; rr < 16; ++rr) tm[rr] = fmaxf(sa0[rr], sb0[rr]);
        if (act1) {
            #pragma unroll
            for (int rr = 0; rr < 16; ++rr)
                tm[rr] = fmaxf(tm[rr], fmaxf(sa1[rr], sb1[rr]));
        }
        #pragma unroll
        for (int s = 8; s > 0; s >>= 1)
            #pragma unroll
            for (int rr = 0; rr < s; ++rr) tm[rr] = fmaxf(tm[rr], tm[rr + s]);
        float pmax = fmaxf(tm[0], __shfl_xor(tm[0], 32));

        // single defer-max (T13) per 128 cols
        if (__any(pmax > mrun + 8.0f)) {
            const float mnew  = fmaxf(mrun, pmax);
            const float alpha = exp2f((mrun - mnew) * LOG2E);
            mrun = mnew;
            lrun *= alpha;
            #pragma unroll
            for (int rr = 0; rr < 16; ++rr) {
                const float ar = __shfl(alpha, (rr & 3) + 8 * (rr >> 2) + 4 * hi);
                o0[rr] *= ar; o1[rr] *= ar;
            }
        }

        const float mb = mrun * LOG2E;
        #pragma unroll
        for (int rr = 0; rr < 16; ++rr) {
            sa0[rr] = exp2f(fmaf(sa0[rr], LOG2E, -mb));
            sb0[rr] = exp2f(fmaf(sb0[rr], LOG2E, -mb));
        }
        if (act1) {
            #pragma unroll
            for (int rr = 0; rr < 16; ++rr) {
                sa1[rr] = exp2f(fmaf(sa1[rr], LOG2E, -mb));
                sb1[rr] = exp2f(fmaf(sb1[rr], LOG2E, -mb));
            }
        }

        // combined sum tree
        float tu[16];
        #pragma unroll
        for (int rr = 0; rr < 16; ++rr) tu[rr] = sa0[rr] + sb0[rr];
        if (act1) {
            #pragma unroll
            for (int rr = 0; rr < 16; ++rr) tu[rr] += sa1[rr] + sb1[rr];
        }
        #pragma unroll
        for (int s = 8; s > 0; s >>= 1)
            #pragma unroll
            for (int rr = 0; rr < s; ++rr) tu[rr] += tu[rr + s];
        lrun += tu[0] + __shfl_xor(tu[0], 32);

        // pack + PV, half 0
        {
            unsigned paw[4][4];
            #pragma unroll
            for (int ks = 0; ks < 4; ++ks) {
                const int e = 2 * ks, f = 2 * ks + 1;
                const int ra = 4 * (e & 3), rb = 4 * (f & 3);
                unsigned A0, A1, B0, B1;
                if (e >> 2) { A0 = pk_bf16(sb0[ra], sb0[ra + 1]); A1 = pk_bf16(sb0[ra + 2], sb0[ra + 3]); }
                else        { A0 = pk_bf16(sa0[ra], sa0[ra + 1]); A1 = pk_bf16(sa0[ra + 2], sa0[ra + 3]); }
                if (f >> 2) { B0 = pk_bf16(sb0[rb], sb0[rb + 1]); B1 = pk_bf16(sb0[rb + 2], sb0[rb + 3]); }
                else        { B0 = pk_bf16(sa0[rb], sa0[rb + 1]); B1 = pk_bf16(sa0[rb + 2], sa0[rb + 3]); }
                pl32_swap(A0, B0);
                pl32_swap(A1, B1);
                paw[ks][0] = A0; paw[ks][1] = A1; paw[ks][2] = B0; paw[ks][3] = B1;
            }
            #pragma unroll
            for (int ks = 0; ks < 4; ++ks) {
                union { unsigned w[4]; bf16x8 v; } u;
                u.w[0] = paw[ks][0]; u.w[1] = paw[ks][1];
                u.w[2] = paw[ks][2]; u.w[3] = paw[ks][3];
                const bf16x8 v0 = *(const bf16x8*)&lV[p][0][ql]     [((2 * ks + hi) ^ qkey) * 8];
                const bf16x8 v1 = *(const bf16x8*)&lV[p][0][32 + ql][((2 * ks + hi) ^ qkey) * 8];
                o0 = MFMA32(u.v, v0, o0);
                o1 = MFMA32(u.v, v1, o1);
            }
        }
        // pack + PV, half 1
        if (act1) {
            unsigned paw[4][4];
            #pragma unroll
            for (int ks = 0; ks < 4; ++ks) {
                const int e = 2 * ks, f = 2 * ks + 1;
                const int ra = 4 * (e & 3), rb = 4 * (f & 3);
                unsigned A0, A1, B0, B1;
                if (e >> 2) { A0 = pk_bf16(sb1[ra], sb1[ra + 1]); A1 = pk_bf16(sb1[ra + 2], sb1[ra + 3]); }
                else        { A0 = pk_bf16(sa1[ra], sa1[ra + 1]); A1 = pk_bf16(sa1[ra + 2], sa1[ra + 3]); }
                if (f >> 2) { B0 = pk_bf16(sb1[rb], sb1[rb + 1]); B1 = pk_bf16(sb1[rb + 2], sb1[rb + 3]); }
                else        { B0 = pk_bf16(sa1[rb], sa1[rb + 1]); B1 = pk_bf16(sa1[rb + 2], sa1[rb + 3]); }
                pl32_swap(A0, B0);
                pl32_swap(A1, B1);
                paw[ks][0] = A0; paw[ks][1] = A1; paw[ks][2] = B0; paw[ks][3] = B1;
            }
            #pragma unroll
            for (int ks = 0; ks < 4; ++ks) {
                union { unsigned w[4]; bf16x8 v; } u;
                u.w[0] = paw[ks][0]; u.w[1] = paw[ks][1];
                u.w[2] = paw[ks][2]; u.w[3] = paw[ks][3];
                const bf16x8 v0 = *(const bf16x8*)&lV[p][1][ql]     [((2 * ks + hi) ^ qkey) * 8];
                const bf16x8 v1 = *(const bf16x8*)&lV[p][1][32 + ql][((2 * ks + hi) ^ qkey) * 8];
                o0 = MFMA32(u.v, v0, o0);
                o1 = MFMA32(u.v, v1, o1);
            }
        }
    }

    // epilogue
    const float linv = 1.0f / fmaxf(lrun, 1e-30f);
    #pragma unroll
    for (int rr = 0; rr < 16; ++rr) {
        const int cr = (rr & 3) + 8 * (rr >> 2) + 4 * hi;
        const float li = __shfl(linv, cr);
        const int row = wrow0 + cr;
        O[(size_t)row * 64 + ql]      = f2bf(o0[rr] * li);
        O[(size_t)row * 64 + 32 + ql] = f2bf(o1[rr] * li);
    }
}

extern "C" void kernel_launch(void* const* d_in, const int* in_sizes, int n_in,
                              void* d_out, int out_size, void* d_ws, size_t ws_size,
                              hipStream_t stream) {
    const float* x  = (const float*)d_in[0];   // x_q  [4,2048,512] fp32
    const float* Wq = (const float*)d_in[1];   // [8,64,512] fp32
    const float* Wk = (const float*)d_in[2];
    const float* Wv = (const float*)d_in[3];
    const float* Wp = (const float*)d_in[4];   // [512,512] fp32
    const float* bp = (const float*)d_in[5];   // [512] fp32
    float* out = (float*)d_out;                // [4,2048,512] fp32

    const size_t NEL  = 4u * 8u * 2048u * 64u;   // 4,194,304 (all batches)
    const size_t NELB = 8u * 2048u * 64u;        // 1,048,576 (one batch)
    const float qscale = 0.04419417382415922f;   // 512^-0.5 folded into q

    if (ws_size >= 3u * NEL * sizeof(ushort)) {
        ushort* xbf  = (ushort*)d_out;
        ushort* qb   = xbf + NEL;
        ushort* kb   = (ushort*)d_ws;
        ushort* vb   = kb + NEL;                 // holds VT [b,h,d,2048]
        ushort* ab   = vb + NEL;
        ushort* wbf  = ab;                       // 1.5 MB, consumed pre-attn
        ushort* wpbf = kb;                       // 0.5 MB, valid post-attn
        hipLaunchKernelGGL(cvt_fused, dim3((int)(NEL / (256 * 8)) + 384), dim3(256), 0, stream,
                           x, xbf, (int)NEL, (int)(NEL / (256 * 8)), Wq, Wk, Wv, wbf);
        hipLaunchKernelGGL(gemm_qkv3, dim3(64, 12), dim3(256), 0, stream,
                           xbf, wbf, qscale, qb, kb, vb);
        hipLaunchKernelGGL(attn_kernel, dim3(16, 32), dim3(256), 0, stream, qb, kb, vb, ab);
        hipLaunchKernelGGL(cvt_bf16, dim3(128), dim3(256), 0, stream, Wp, wpbf, 262144);
        hipLaunchKernelGGL(gemm_out, dim3(64, 4), dim3(256), 0, stream, ab, wpbf, bp, out);
    } else {
        // per-batch fallback: ws need = 3 * NELB * 2 = 6.3 MB
        ushort* kb  = (ushort*)d_ws;
        ushort* vb  = kb + NELB;
        ushort* ab  = vb + NELB;
        ushort* wbf = ab;
        for (int b = 0; b < 4; ++b) {
            const float* xb = x + (size_t)b * 2048u * 512u;
            float* ob = out + (size_t)b * 2048u * 512u;
            ushort* xbf  = (ushort*)ob;
            ushort* qb   = xbf + NELB;
            ushort* wpbf = kb;
            hipLaunchKernelGGL(cvt_fused, dim3((int)(NELB / (256 * 8)) + 384), dim3(256), 0, stream,
                               xb, xbf, (int)NELB, (int)(NELB / (256 * 8)), Wq, Wk, Wv, wbf);
            hipLaunchKernelGGL(gemm_qkv3, dim3(16, 12), dim3(256), 0, stream,
                               xbf, wbf, qscale, qb, kb, vb);
            hipLaunchKernelGGL(attn_kernel, dim3(16, 8), dim3(256), 0, stream, qb, kb, vb, ab);
            hipLaunchKernelGGL(cvt_bf16, dim3(128), dim3(256), 0, stream, Wp, wpbf, 262144);
            hipLaunchKernelGGL(gemm_out, dim3(16, 4), dim3(256), 0, stream, ab, wpbf, bp, ob);
        }
    }
}